// Round 4
// baseline (1210.584 us; speedup 1.0000x reference)
//
#include <hip/hip_runtime.h>
#include <hip/hip_cooperative_groups.h>
#include <math.h>

namespace cg = cooperative_groups;

#define BB    256      // batch
#define DIN   512
#define HD    512
#define DOUT  10
#define NS    32       // samples
#define NIDX  2560     // BB*DOUT
#define MAXIT 10
#define CG_EPS 1e-12f
#define NBLK  160      // fused CG: blocks (16 rows each)
#define NTHR  512      // fused CG: threads (8 waves)

typedef __attribute__((ext_vector_type(8))) short s16x8;   // 8 bf16 (4 VGPRs)
typedef __attribute__((ext_vector_type(4))) float f32x4;   // 4 fp32 acc

// ---------------- helpers ----------------
__device__ __forceinline__ unsigned short f2bf(float f){
  unsigned u = __float_as_uint(f);
  return (unsigned short)((u + 0x7FFFu + ((u >> 16) & 1u)) >> 16);
}
__device__ __forceinline__ float bf2f(unsigned short h){
  return __uint_as_float((unsigned)h << 16);
}

// ---------------- forward: h, G ----------------
__global__ __launch_bounds__(256) void k_gemm_z(
    const float* __restrict__ x, const float* __restrict__ W1,
    const float* __restrict__ b1, float* __restrict__ h, float* __restrict__ G)
{
  __shared__ __align__(16) float Al[16][68];
  __shared__ __align__(16) float Bl[16][64];
  const int tid = threadIdx.x;
  const int m0 = blockIdx.y * 64, n0 = blockIdx.x * 64;
  const int tx = tid & 15, ty = tid >> 4;
  float acc[4][4] = {};
  for (int k0 = 0; k0 < DIN; k0 += 16){
    {
      int m = tid >> 2, kk = (tid & 3) << 2;
      float4 a = *(const float4*)(x + (size_t)(m0+m)*DIN + k0 + kk);
      Al[kk+0][m]=a.x; Al[kk+1][m]=a.y; Al[kk+2][m]=a.z; Al[kk+3][m]=a.w;
    }
    {
      int kk = tid >> 4, n = (tid & 15) << 2;
      *(float4*)&Bl[kk][n] = *(const float4*)(W1 + (size_t)(k0+kk)*HD + n0 + n);
    }
    __syncthreads();
    #pragma unroll
    for (int kk = 0; kk < 16; kk++){
      float4 av = *(const float4*)&Al[kk][ty<<2];
      float4 bv = *(const float4*)&Bl[kk][tx<<2];
      float aa[4]={av.x,av.y,av.z,av.w}, bb[4]={bv.x,bv.y,bv.z,bv.w};
      #pragma unroll
      for (int i=0;i<4;i++)
        #pragma unroll
        for (int j=0;j<4;j++) acc[i][j] += aa[i]*bb[j];
    }
    __syncthreads();
  }
  float4 b4 = *(const float4*)&b1[n0 + (tx<<2)];
  float bbv[4] = {b4.x,b4.y,b4.z,b4.w};
  #pragma unroll
  for (int i=0;i<4;i++){
    int m = m0 + (ty<<2) + i;
    float hh[4], gg[4];
    #pragma unroll
    for (int j=0;j<4;j++){ float t = tanhf(acc[i][j] + bbv[j]); hh[j]=t; gg[j]=1.0f-t*t; }
    *(float4*)&h[(size_t)m*HD + n0 + (tx<<2)] = make_float4(hh[0],hh[1],hh[2],hh[3]);
    *(float4*)&G[(size_t)m*HD + n0 + (tx<<2)] = make_float4(gg[0],gg[1],gg[2],gg[3]);
  }
}

// ---------------- Kx = x x^T + 1 ; Kh = h h^T + 1 ----------------
__global__ __launch_bounds__(256) void k_gemm_kxkh(
    const float* __restrict__ x, const float* __restrict__ h,
    float* __restrict__ Kx, float* __restrict__ Kh)
{
  __shared__ __align__(16) float Al[16][68];
  __shared__ __align__(16) float Bl[16][68];
  const int tid = threadIdx.x;
  const float* A = blockIdx.z ? h : x;
  float* C = blockIdx.z ? Kh : Kx;
  const int m0 = blockIdx.y * 64, n0 = blockIdx.x * 64;
  const int tx = tid & 15, ty = tid >> 4;
  float acc[4][4] = {};
  for (int k0 = 0; k0 < DIN; k0 += 16){
    {
      int m = tid >> 2, kk = (tid & 3) << 2;
      float4 a = *(const float4*)(A + (size_t)(m0+m)*DIN + k0 + kk);
      Al[kk+0][m]=a.x; Al[kk+1][m]=a.y; Al[kk+2][m]=a.z; Al[kk+3][m]=a.w;
      float4 b = *(const float4*)(A + (size_t)(n0+m)*DIN + k0 + kk);
      Bl[kk+0][m]=b.x; Bl[kk+1][m]=b.y; Bl[kk+2][m]=b.z; Bl[kk+3][m]=b.w;
    }
    __syncthreads();
    #pragma unroll
    for (int kk = 0; kk < 16; kk++){
      float4 av = *(const float4*)&Al[kk][ty<<2];
      float4 bv = *(const float4*)&Bl[kk][tx<<2];
      float aa[4]={av.x,av.y,av.z,av.w}, bb[4]={bv.x,bv.y,bv.z,bv.w};
      #pragma unroll
      for (int i=0;i<4;i++)
        #pragma unroll
        for (int j=0;j<4;j++) acc[i][j] += aa[i]*bb[j];
    }
    __syncthreads();
  }
  #pragma unroll
  for (int i=0;i<4;i++){
    int m = m0 + (ty<<2) + i;
    *(float4*)&C[(size_t)m*BB + n0 + (tx<<2)] =
        make_float4(acc[i][0]+1.0f, acc[i][1]+1.0f, acc[i][2]+1.0f, acc[i][3]+1.0f);
  }
}

// ---------------- E2 = [Ehi | Elo] bf16, E[(b,o)][j] = G[b][j]*W2[j][o] ----------------
__global__ __launch_bounds__(256) void k_buildE(
    const float* __restrict__ G, const float* __restrict__ W2,
    unsigned short* __restrict__ E2)
{
  int gid = blockIdx.x * 256 + threadIdx.x;   // 2560 rows * 128 j4-chunks
  int row = gid >> 7, j4 = (gid & 127) << 2;
  int b = row / 10, o = row - b * 10;
  float4 g = *(const float4*)&G[(size_t)b*HD + j4];
  float e[4] = { g.x * W2[(j4+0)*DOUT + o], g.y * W2[(j4+1)*DOUT + o],
                 g.z * W2[(j4+2)*DOUT + o], g.w * W2[(j4+3)*DOUT + o] };
  unsigned short hi[4], lo[4];
  #pragma unroll
  for (int r = 0; r < 4; r++){
    hi[r] = f2bf(e[r]);
    lo[r] = f2bf(e[r] - bf2f(hi[r]));
  }
  *(ushort4*)&E2[(size_t)row*1024 + j4]       = make_ushort4(hi[0],hi[1],hi[2],hi[3]);
  *(ushort4*)&E2[(size_t)row*1024 + 512 + j4] = make_ushort4(lo[0],lo[1],lo[2],lo[3]);
}

// ---------------- x2 = [xhi | xlo] bf16 ----------------
__global__ __launch_bounds__(256) void k_prepx(
    const float* __restrict__ x, unsigned short* __restrict__ x2)
{
  int gid = blockIdx.x * 256 + threadIdx.x;   // 256 rows * 128 j4-chunks
  int row = gid >> 7, j4 = (gid & 127) << 2;
  float4 v = *(const float4*)&x[(size_t)row*DIN + j4];
  float e[4] = {v.x, v.y, v.z, v.w};
  unsigned short hi[4], lo[4];
  #pragma unroll
  for (int r = 0; r < 4; r++){
    hi[r] = f2bf(e[r]);
    lo[r] = f2bf(e[r] - bf2f(hi[r]));
  }
  *(ushort4*)&x2[(size_t)row*1024 + j4]       = make_ushort4(hi[0],hi[1],hi[2],hi[3]);
  *(ushort4*)&x2[(size_t)row*1024 + 512 + j4] = make_ushort4(lo[0],lo[1],lo[2],lo[3]);
}

// ---------------- M2 = split-bf16 of (Kx .* (E E^T) + delta_{oo'} Kh) ----------------
// 820 upper-tri 64x64 tiles, 1 wave/block, 3-phase split-bf16 MFMA (as verified R3).
__global__ void k_gemm_M(
    const unsigned short* __restrict__ E2, const float* __restrict__ Kx,
    const float* __restrict__ Kh, unsigned short* __restrict__ M2)
{
  const int tid = threadIdx.x;        // 0..63
  int t = blockIdx.x, bi = 0;
  while (t >= 40 - bi){ t -= 40 - bi; bi++; }
  const int bj = bi + t;
  const int m0 = bi << 6, n0 = bj << 6;
  const int ln = tid & 15, kq = tid >> 4;

  const unsigned short* pa[4];
  const unsigned short* pb[4];
  #pragma unroll
  for (int f = 0; f < 4; f++){
    pa[f] = E2 + (size_t)(m0 + f*16 + ln) * 1024 + kq * 8;
    pb[f] = E2 + (size_t)(n0 + f*16 + ln) * 1024 + kq * 8;
  }

  f32x4 acc[4][4];
  #pragma unroll
  for (int i = 0; i < 4; i++)
    #pragma unroll
    for (int j = 0; j < 4; j++)
      acc[i][j] = (f32x4){0.f, 0.f, 0.f, 0.f};

  s16x8 a0[4], b0[4], a1[4], b1[4];

#define LOAD_AB(Aset, Bset, s) do{                                        \
    const int _ph = (s) >> 4, _kk = ((s) & 15) << 5;                      \
    const int _oa = (_ph == 2 ? 512 : 0) + _kk;                           \
    const int _ob = (_ph == 1 ? 512 : 0) + _kk;                           \
    Aset[0] = *(const s16x8*)(pa[0] + _oa);                               \
    Aset[1] = *(const s16x8*)(pa[1] + _oa);                               \
    Aset[2] = *(const s16x8*)(pa[2] + _oa);                               \
    Aset[3] = *(const s16x8*)(pa[3] + _oa);                               \
    Bset[0] = *(const s16x8*)(pb[0] + _ob);                               \
    Bset[1] = *(const s16x8*)(pb[1] + _ob);                               \
    Bset[2] = *(const s16x8*)(pb[2] + _ob);                               \
    Bset[3] = *(const s16x8*)(pb[3] + _ob);                               \
  }while(0)

#define MFMA_AB(Aset, Bset) do{                                           \
    _Pragma("unroll")                                                     \
    for (int fi = 0; fi < 4; fi++){                                       \
      _Pragma("unroll")                                                   \
      for (int fj = 0; fj < 4; fj++)                                      \
        acc[fi][fj] = __builtin_amdgcn_mfma_f32_16x16x32_bf16(            \
            Aset[fi], Bset[fj], acc[fi][fj], 0, 0, 0);                    \
    }                                                                     \
  }while(0)

  LOAD_AB(a0, b0, 0);
  for (int it = 0; it < 24; ++it){
    const int s1 = 2*it + 1;
    LOAD_AB(a1, b1, s1);
    MFMA_AB(a0, b0);
    const int s2 = 2*it + 2;
    if (s2 < 48) LOAD_AB(a0, b0, s2);
    MFMA_AB(a1, b1);
  }
#undef LOAD_AB
#undef MFMA_AB

  int bmv[4][4], omv[4][4], bnv[4], onv[4];
  #pragma unroll
  for (int f = 0; f < 4; f++){
    int n = n0 + f*16 + ln; bnv[f] = n / 10; onv[f] = n - bnv[f]*10;
    #pragma unroll
    for (int r = 0; r < 4; r++){
      int m = m0 + f*16 + kq*4 + r;
      bmv[f][r] = m / 10; omv[f][r] = m - bmv[f][r]*10;
    }
  }
  #pragma unroll
  for (int fi = 0; fi < 4; fi++)
    #pragma unroll
    for (int r = 0; r < 4; r++){
      const int m = m0 + fi*16 + kq*4 + r;
      #pragma unroll
      for (int fj = 0; fj < 4; fj++){
        const int n = n0 + fj*16 + ln;
        float v = Kx[(size_t)bmv[fi][r]*BB + bnv[fj]] * acc[fi][fj][r];
        if (omv[fi][r] == onv[fj]) v += Kh[(size_t)bmv[fi][r]*BB + bnv[fj]];
        unsigned short hv = f2bf(v);
        unsigned short lv = f2bf(v - bf2f(hv));
        M2[(size_t)m*5120 + n]        = hv;
        M2[(size_t)m*5120 + 2560 + n] = lv;
        if (bi != bj){
          M2[(size_t)n*5120 + m]        = hv;
          M2[(size_t)n*5120 + 2560 + m] = lv;
        }
      }
    }
}

// ---------------- T[s] = (x @ eps_W1[s] + eps_b1[s]) * G  via split-bf16 MFMA ----------------
// 1024 blocks x 64 thr; 64x64 tile; B (eW1 columns) split hi/lo on the fly.
__global__ void k_gemm_T(
    const unsigned short* __restrict__ x2, const float* __restrict__ eW1,
    const float* __restrict__ eb1, const float* __restrict__ G,
    float* __restrict__ T)
{
  const int l = threadIdx.x;
  const int bid = blockIdx.x;
  const int s = bid >> 5, rem = bid & 31;
  const int m0 = (rem & 3) << 6, n0 = (rem >> 2) << 6;
  const int ln = l & 15, kq = l >> 4;
  const float* Wb = eW1 + (size_t)s * DIN * HD;

  const unsigned short* pa[4];
  #pragma unroll
  for (int f = 0; f < 4; f++) pa[f] = x2 + (size_t)(m0 + 16*f + ln) * 1024 + kq * 8;

  f32x4 acc[4][4];
  #pragma unroll
  for (int i = 0; i < 4; i++)
    #pragma unroll
    for (int j = 0; j < 4; j++)
      acc[i][j] = (f32x4){0.f, 0.f, 0.f, 0.f};

  #pragma unroll 2
  for (int k0 = 0; k0 < DIN; k0 += 32){
    float wv[4][8];
    const float* wp = Wb + (size_t)(k0 + kq*8)*HD + n0 + ln;
    #pragma unroll
    for (int i = 0; i < 8; i++)
      #pragma unroll
      for (int f = 0; f < 4; f++)
        wv[f][i] = wp[(size_t)i*HD + 16*f];

    s16x8 ahi[4], alo[4], bhi[4], blo[4];
    #pragma unroll
    for (int f = 0; f < 4; f++){
      ahi[f] = *(const s16x8*)(pa[f] + k0);
      alo[f] = *(const s16x8*)(pa[f] + 512 + k0);
      #pragma unroll
      for (int i = 0; i < 8; i++){
        unsigned short hh = f2bf(wv[f][i]);
        bhi[f][i] = (short)hh;
        blo[f][i] = (short)f2bf(wv[f][i] - bf2f(hh));
      }
    }
    #pragma unroll
    for (int fi = 0; fi < 4; fi++)
      #pragma unroll
      for (int fj = 0; fj < 4; fj++){
        acc[fi][fj] = __builtin_amdgcn_mfma_f32_16x16x32_bf16(ahi[fi], bhi[fj], acc[fi][fj], 0,0,0);
        acc[fi][fj] = __builtin_amdgcn_mfma_f32_16x16x32_bf16(ahi[fi], blo[fj], acc[fi][fj], 0,0,0);
        acc[fi][fj] = __builtin_amdgcn_mfma_f32_16x16x32_bf16(alo[fi], bhi[fj], acc[fi][fj], 0,0,0);
      }
  }

  #pragma unroll
  for (int fj = 0; fj < 4; fj++){
    const int n = n0 + 16*fj + ln;
    const float eb = eb1[(size_t)s*HD + n];
    #pragma unroll
    for (int fi = 0; fi < 4; fi++)
      #pragma unroll
      for (int q = 0; q < 4; q++){
        const int m = m0 + 16*fi + kq*4 + q;
        T[((size_t)s*BB + m)*HD + n] = (acc[fi][fj][q] + eb) * G[(size_t)m*HD + n];
      }
  }
}

// ---------------- bvec (+ out0 for s==0 blocks) ----------------
__global__ __launch_bounds__(256) void k_bvec(
    const float* __restrict__ T, const float* __restrict__ W2,
    const float* __restrict__ h, const float* __restrict__ eW2,
    const float* __restrict__ eb2, const float* __restrict__ b2,
    float* __restrict__ bvec, float* __restrict__ out0)
{
  __shared__ __align__(16) float W2t[10][516];
  __shared__ __align__(16) float E2t[10][516];
  const int tid = threadIdx.x, bid = blockIdx.x;
  const int s = bid / 10;
  const int idx = (bid % 10) * 256 + tid;
  const int b = idx / 10, o = idx - b*10;
  const float* e2 = eW2 + (size_t)s * HD * DOUT;
  for (int i = tid; i < HD*DOUT; i += 256){
    int k = i / 10, oo = i - k*10;
    W2t[oo][k] = W2[i];
    E2t[oo][k] = e2[i];
  }
  __syncthreads();
  const float* Tr = T + ((size_t)s*BB + b) * HD;
  const float* hr = h + (size_t)b * HD;
  const bool do0 = (bid < 10);
  float acc = eb2[s*DOUT + o];
  float a0 = 0.f;
  #pragma unroll 4
  for (int k4 = 0; k4 < HD/4; k4++){
    float4 t4 = *(const float4*)(Tr + (k4<<2));
    float4 h4 = *(const float4*)(hr + (k4<<2));
    float4 w4 = *(const float4*)&W2t[o][k4<<2];
    float4 q4 = *(const float4*)&E2t[o][k4<<2];
    acc += t4.x*w4.x + t4.y*w4.y + t4.z*w4.z + t4.w*w4.w
         + h4.x*q4.x + h4.y*q4.y + h4.z*q4.z + h4.w*q4.w;
    if (do0) a0 += h4.x*w4.x + h4.y*w4.y + h4.z*w4.z + h4.w*w4.w;
  }
  bvec[(size_t)s*NIDX + idx] = acc;
  if (do0) out0[idx] = a0 + b2[o];
}

// ---------------- fused CG: init + 10 steps + final Ma + output ----------------
// cooperative, 160 blocks x 512 thr. Block b owns rows [16b,16b+16) for all 32 samples.
// Thread state (registers): acur,rcur,pcur,bval,bas[0..9]. element (s=tid>>4, r=R0+(tid&15)).
__device__ __forceinline__ float block_matvec(
    const unsigned short* __restrict__ M2, const unsigned short* __restrict__ q2,
    int R0, int w, int l, int ln, int kq, int rl, int s,
    float red[8][16][33])
{
  f32x4 acc0 = {0.f,0.f,0.f,0.f}, acc1 = {0.f,0.f,0.f,0.f};
  const unsigned short* arow = M2 + (size_t)(R0 + ln) * 5120;
  const unsigned short* q0 = q2 + (size_t)ln * 5120;
  const unsigned short* q1 = q2 + (size_t)(16 + ln) * 5120;
  #pragma unroll 2
  for (int st = 0; st < 10; ++st){
    const int off = (w*10 + st)*32 + kq*8;
    s16x8 ah  = *(const s16x8*)(arow + off);
    s16x8 al  = *(const s16x8*)(arow + 2560 + off);
    s16x8 b0h = *(const s16x8*)(q0 + off);
    s16x8 b0l = *(const s16x8*)(q0 + 2560 + off);
    s16x8 b1h = *(const s16x8*)(q1 + off);
    s16x8 b1l = *(const s16x8*)(q1 + 2560 + off);
    acc0 = __builtin_amdgcn_mfma_f32_16x16x32_bf16(ah, b0h, acc0, 0,0,0);
    acc1 = __builtin_amdgcn_mfma_f32_16x16x32_bf16(ah, b1h, acc1, 0,0,0);
    acc0 = __builtin_amdgcn_mfma_f32_16x16x32_bf16(ah, b0l, acc0, 0,0,0);
    acc1 = __builtin_amdgcn_mfma_f32_16x16x32_bf16(ah, b1l, acc1, 0,0,0);
    acc0 = __builtin_amdgcn_mfma_f32_16x16x32_bf16(al, b0h, acc0, 0,0,0);
    acc1 = __builtin_amdgcn_mfma_f32_16x16x32_bf16(al, b1h, acc1, 0,0,0);
  }
  __syncthreads();   // previous red consumers done
  #pragma unroll
  for (int q = 0; q < 4; q++){
    red[w][(l>>4)*4 + q][ln]      = acc0[q];
    red[w][(l>>4)*4 + q][16 + ln] = acc1[q];
  }
  __syncthreads();
  float ap = 0.f;
  #pragma unroll
  for (int ww = 0; ww < 8; ww++) ap += red[ww][rl][s];
  return ap;
}

__global__ __launch_bounds__(NTHR) void k_cgfused(
    const unsigned short* __restrict__ M2, const float* __restrict__ bvec,
    unsigned short* __restrict__ ps2, unsigned short* __restrict__ as2,
    float* __restrict__ pAp_part, float* __restrict__ c_part,
    float* __restrict__ rr_part,
    const float* __restrict__ out0, const float* __restrict__ lp,
    const float* __restrict__ lsi, float* __restrict__ out)
{
  cg::grid_group grid = cg::this_grid();
  const int b = blockIdx.x, tid = threadIdx.x;
  const int R0 = b * 16;
  const int s = tid >> 4, rl = tid & 15;
  const int w = tid >> 6, l = tid & 63;
  const int ln = l & 15, kq = l >> 4;

  __shared__ float red[8][16][33];
  __shared__ float bc[32];
  __shared__ float rrL[32];
  __shared__ float cjL[10][32];

  float acur = 0.f, rcur, pcur, bas[10];
  #pragma unroll
  for (int j = 0; j < 10; j++) bas[j] = 0.f;

  const float bval = bvec[(size_t)s*NIDX + R0 + rl];
  rcur = pcur = bval;
  // rr0 partial (reduce over rl within 16-lane group)
  {
    float v = bval * bval;
    #pragma unroll
    for (int o = 8; o > 0; o >>= 1) v += __shfl_down(v, o, 16);
    if (rl == 0) rr_part[s*NBLK + b] = v;
  }
  // write ps2 = split(p)
  {
    unsigned short hh = f2bf(pcur);
    ps2[(size_t)s*5120 + R0 + rl]        = hh;
    ps2[(size_t)s*5120 + 2560 + R0 + rl] = f2bf(pcur - bf2f(hh));
  }
  grid.sync();                                   // S0

  // rr0 all-reduce
  {
    float v = 0.f;
    #pragma unroll
    for (int i = 0; i < 10; i++) v += rr_part[(size_t)(tid>>4)*NBLK + (tid&15) + 16*i];
    #pragma unroll
    for (int o = 8; o > 0; o >>= 1) v += __shfl_down(v, o, 16);
    if ((tid & 15) == 0) rrL[tid>>4] = v;
  }
  __syncthreads();
  bas[0] = bval / (sqrtf(rrL[s]) + CG_EPS);

  for (int k = 0; k < MAXIT; k++){
    const float ap = block_matvec(M2, ps2, R0, w, l, ln, kq, rl, s, red);
    // pAp partial
    {
      float v = pcur * ap;
      #pragma unroll
      for (int o = 8; o > 0; o >>= 1) v += __shfl_down(v, o, 16);
      if (rl == 0) pAp_part[s*NBLK + b] = v;
    }
    grid.sync();                                 // S1
    {
      float v = 0.f;
      #pragma unroll
      for (int i = 0; i < 10; i++) v += pAp_part[(size_t)(tid>>4)*NBLK + (tid&15) + 16*i];
      #pragma unroll
      for (int o = 8; o > 0; o >>= 1) v += __shfl_down(v, o, 16);
      if ((tid & 15) == 0) bc[tid>>4] = v;
    }
    __syncthreads();
    const float alpha = rrL[s] / (bc[s] + CG_EPS);
    acur += alpha * pcur;
    float rn = rcur - alpha * ap;

    if (k < MAXIT - 1){
      // Gram-Schmidt coefficient partials, j = 0..k (compile-time indices)
      #pragma unroll
      for (int j = 0; j < 10; j++){
        if (j <= k){
          float v = bas[j] * rn;
          #pragma unroll
          for (int o = 8; o > 0; o >>= 1) v += __shfl_down(v, o, 16);
          if (rl == 0) c_part[(size_t)(j*NS + s)*NBLK + b] = v;
        }
      }
      grid.sync();                               // S2
      if ((tid >> 5) <= k){
        const int j = tid >> 5, s2 = tid & 31;
        float v = 0.f;
        #pragma unroll 16
        for (int i = 0; i < NBLK; i++) v += c_part[(size_t)(j*NS + s2)*NBLK + i];
        cjL[j][s2] = v;
      }
      __syncthreads();
      #pragma unroll
      for (int j = 0; j < 10; j++)
        if (j <= k) rn -= bas[j] * cjL[j][s];
      // rr partial
      {
        float v = rn * rn;
        #pragma unroll
        for (int o = 8; o > 0; o >>= 1) v += __shfl_down(v, o, 16);
        if (rl == 0) rr_part[s*NBLK + b] = v;
      }
      grid.sync();                               // S3
      {
        float v = 0.f;
        #pragma unroll
        for (int i = 0; i < 10; i++) v += rr_part[(size_t)(tid>>4)*NBLK + (tid&15) + 16*i];
        #pragma unroll
        for (int o = 8; o > 0; o >>= 1) v += __shfl_down(v, o, 16);
        if ((tid & 15) == 0) bc[tid>>4] = v;
      }
      __syncthreads();
      const float rrn = bc[s];
      const float beta = rrn / (rrL[s] + CG_EPS);
      pcur = rn + beta * pcur;
      rcur = rn;
      const float bnew = rn / (sqrtf(rrn) + CG_EPS);
      #pragma unroll
      for (int j = 1; j < 10; j++)
        if (j == k + 1) bas[j] = bnew;
      __syncthreads();
      if ((tid & 15) == 0) rrL[tid>>4] = bc[tid>>4];
      // write ps2 = split(p)
      {
        unsigned short hh = f2bf(pcur);
        ps2[(size_t)s*5120 + R0 + rl]        = hh;
        ps2[(size_t)s*5120 + 2560 + R0 + rl] = f2bf(pcur - bf2f(hh));
      }
      grid.sync();                               // S4
    }
  }

  // final: Ma = M @ a ; out = out0 + si*b + (sk-si)*Ma
  {
    unsigned short hh = f2bf(acur);
    as2[(size_t)s*5120 + R0 + rl]        = hh;
    as2[(size_t)s*5120 + 2560 + R0 + rl] = f2bf(acur - bf2f(hh));
  }
  grid.sync();                                   // S5
  const float ma = block_matvec(M2, as2, R0, w, l, ln, kq, rl, s, red);
  const float sk = expf(-0.5f * lp[0]);
  const float si = expf(lsi[0]);
  out[(size_t)s*NIDX + R0 + rl] = out0[R0 + rl] + si * bval + (sk - si) * ma;
}

// ---------------- launch ----------------
extern "C" void kernel_launch(void* const* d_in, const int* in_sizes, int n_in,
                              void* d_out, int out_size, void* d_ws, size_t ws_size,
                              hipStream_t stream)
{
  const float* x   = (const float*)d_in[0];
  const float* W1  = (const float*)d_in[1];
  const float* b1  = (const float*)d_in[2];
  const float* W2  = (const float*)d_in[3];
  const float* b2  = (const float*)d_in[4];
  const float* eW1 = (const float*)d_in[5];
  const float* eb1 = (const float*)d_in[6];
  const float* eW2 = (const float*)d_in[7];
  const float* eb2 = (const float*)d_in[8];
  const float* lp  = (const float*)d_in[9];
  const float* lsi = (const float*)d_in[10];
  float* outp = (float*)d_out;

  float* ws = (float*)d_ws;
  float* h        = ws;                       // 131072
  float* G        = h        + 131072;        // 131072
  float* Kx       = G        + 131072;        // 65536
  float* Kh       = Kx       + 65536;         // 65536
  float* E2f      = Kh       + 65536;         // 1310720 (2560x1024 bf16 hi|lo)
  float* x2f      = E2f      + 1310720;       // 131072  (256x1024 bf16 hi|lo)
  float* M2f      = x2f      + 131072;        // 6553600 (2560x5120 bf16 hi|lo); T aliases
  float* out0     = M2f      + 6553600;       // 2560
  float* bvec     = out0     + 2560;          // 81920
  float* ps2f     = bvec     + 81920;         // 81920 (32x5120 bf16 hi|lo)
  float* as2f     = ps2f     + 81920;         // 81920
  float* pAp_part = as2f     + 81920;         // 5120 (32*160)
  float* c_part   = pAp_part + 5120;          // 51200 (10*32*160)
  float* rr_part  = c_part   + 51200;         // 5120
  // total ~8.70M floats = 34.8 MB

  unsigned short* E2 = (unsigned short*)E2f;
  unsigned short* x2 = (unsigned short*)x2f;
  unsigned short* M2 = (unsigned short*)M2f;
  unsigned short* ps2 = (unsigned short*)ps2f;
  unsigned short* as2 = (unsigned short*)as2f;
  float* T = M2f;   // alias: T (4194304 floats) dead before M2 is built

  k_gemm_z   <<<dim3(8,4),   256, 0, stream>>>(x, W1, b1, h, G);
  k_buildE   <<<1280,        256, 0, stream>>>(G, W2, E2);
  k_prepx    <<<128,         256, 0, stream>>>(x, x2);
  k_gemm_kxkh<<<dim3(4,4,2), 256, 0, stream>>>(x, h, Kx, Kh);
  k_gemm_T   <<<1024,        64,  0, stream>>>(x2, eW1, eb1, G, T);
  k_bvec     <<<320,         256, 0, stream>>>(T, W2, h, eW2, eb2, b2, bvec, out0);
  k_gemm_M   <<<820,         64,  0, stream>>>(E2, Kx, Kh, M2);  // overwrites T (dead)

  void* args[] = { (void*)&M2, (void*)&bvec, (void*)&ps2, (void*)&as2,
                   (void*)&pAp_part, (void*)&c_part, (void*)&rr_part,
                   (void*)&out0, (void*)&lp, (void*)&lsi, (void*)&outp };
  hipLaunchCooperativeKernel((void*)k_cgfused, dim3(NBLK), dim3(NTHR),
                             args, 0, stream);
}

// Round 6
// 451.479 us; speedup vs baseline: 2.6814x; 2.6814x over previous
//
#include <hip/hip_runtime.h>
#include <math.h>

#define BB    256      // batch
#define DIN   512
#define HD    512
#define DOUT  10
#define NS    32       // samples
#define NIDX  2560     // BB*DOUT
#define MAXIT 10
#define CG_EPS 1e-12f

typedef __attribute__((ext_vector_type(8))) short s16x8;   // 8 bf16 (4 VGPRs)
typedef __attribute__((ext_vector_type(4))) float f32x4;   // 4 fp32 acc

// ---------------- helpers ----------------
__device__ __forceinline__ float wave_red(float v){
  #pragma unroll
  for (int off = 32; off > 0; off >>= 1) v += __shfl_down(v, off, 64);
  return v;  // lane 0 holds total
}
__device__ __forceinline__ unsigned short f2bf(float f){
  unsigned u = __float_as_uint(f);
  return (unsigned short)((u + 0x7FFFu + ((u >> 16) & 1u)) >> 16);
}
__device__ __forceinline__ float bf2f(unsigned short h){
  return __uint_as_float((unsigned)h << 16);
}

// ---------------- forward: h, G ----------------
__global__ __launch_bounds__(256) void k_gemm_z(
    const float* __restrict__ x, const float* __restrict__ W1,
    const float* __restrict__ b1, float* __restrict__ h, float* __restrict__ G)
{
  __shared__ __align__(16) float Al[16][68];
  __shared__ __align__(16) float Bl[16][64];
  const int tid = threadIdx.x;
  const int m0 = blockIdx.y * 64, n0 = blockIdx.x * 64;
  const int tx = tid & 15, ty = tid >> 4;
  float acc[4][4] = {};
  for (int k0 = 0; k0 < DIN; k0 += 16){
    {
      int m = tid >> 2, kk = (tid & 3) << 2;
      float4 a = *(const float4*)(x + (size_t)(m0+m)*DIN + k0 + kk);
      Al[kk+0][m]=a.x; Al[kk+1][m]=a.y; Al[kk+2][m]=a.z; Al[kk+3][m]=a.w;
    }
    {
      int kk = tid >> 4, n = (tid & 15) << 2;
      *(float4*)&Bl[kk][n] = *(const float4*)(W1 + (size_t)(k0+kk)*HD + n0 + n);
    }
    __syncthreads();
    #pragma unroll
    for (int kk = 0; kk < 16; kk++){
      float4 av = *(const float4*)&Al[kk][ty<<2];
      float4 bv = *(const float4*)&Bl[kk][tx<<2];
      float aa[4]={av.x,av.y,av.z,av.w}, bb[4]={bv.x,bv.y,bv.z,bv.w};
      #pragma unroll
      for (int i=0;i<4;i++)
        #pragma unroll
        for (int j=0;j<4;j++) acc[i][j] += aa[i]*bb[j];
    }
    __syncthreads();
  }
  float4 b4 = *(const float4*)&b1[n0 + (tx<<2)];
  float bbv[4] = {b4.x,b4.y,b4.z,b4.w};
  #pragma unroll
  for (int i=0;i<4;i++){
    int m = m0 + (ty<<2) + i;
    float hh[4], gg[4];
    #pragma unroll
    for (int j=0;j<4;j++){ float t = tanhf(acc[i][j] + bbv[j]); hh[j]=t; gg[j]=1.0f-t*t; }
    *(float4*)&h[(size_t)m*HD + n0 + (tx<<2)] = make_float4(hh[0],hh[1],hh[2],hh[3]);
    *(float4*)&G[(size_t)m*HD + n0 + (tx<<2)] = make_float4(gg[0],gg[1],gg[2],gg[3]);
  }
}

// ---------------- Kx = x x^T + 1 ; Kh = h h^T + 1 ----------------
__global__ __launch_bounds__(256) void k_gemm_kxkh(
    const float* __restrict__ x, const float* __restrict__ h,
    float* __restrict__ Kx, float* __restrict__ Kh)
{
  __shared__ __align__(16) float Al[16][68];
  __shared__ __align__(16) float Bl[16][68];
  const int tid = threadIdx.x;
  const float* A = blockIdx.z ? h : x;
  float* C = blockIdx.z ? Kh : Kx;
  const int m0 = blockIdx.y * 64, n0 = blockIdx.x * 64;
  const int tx = tid & 15, ty = tid >> 4;
  float acc[4][4] = {};
  for (int k0 = 0; k0 < DIN; k0 += 16){
    {
      int m = tid >> 2, kk = (tid & 3) << 2;
      float4 a = *(const float4*)(A + (size_t)(m0+m)*DIN + k0 + kk);
      Al[kk+0][m]=a.x; Al[kk+1][m]=a.y; Al[kk+2][m]=a.z; Al[kk+3][m]=a.w;
      float4 b = *(const float4*)(A + (size_t)(n0+m)*DIN + k0 + kk);
      Bl[kk+0][m]=b.x; Bl[kk+1][m]=b.y; Bl[kk+2][m]=b.z; Bl[kk+3][m]=b.w;
    }
    __syncthreads();
    #pragma unroll
    for (int kk = 0; kk < 16; kk++){
      float4 av = *(const float4*)&Al[kk][ty<<2];
      float4 bv = *(const float4*)&Bl[kk][tx<<2];
      float aa[4]={av.x,av.y,av.z,av.w}, bb[4]={bv.x,bv.y,bv.z,bv.w};
      #pragma unroll
      for (int i=0;i<4;i++)
        #pragma unroll
        for (int j=0;j<4;j++) acc[i][j] += aa[i]*bb[j];
    }
    __syncthreads();
  }
  #pragma unroll
  for (int i=0;i<4;i++){
    int m = m0 + (ty<<2) + i;
    *(float4*)&C[(size_t)m*BB + n0 + (tx<<2)] =
        make_float4(acc[i][0]+1.0f, acc[i][1]+1.0f, acc[i][2]+1.0f, acc[i][3]+1.0f);
  }
}

// ---------------- E2 = [Ehi | Elo] bf16, E[(b,o)][j] = G[b][j]*W2[j][o] ----------------
__global__ __launch_bounds__(256) void k_buildE(
    const float* __restrict__ G, const float* __restrict__ W2,
    unsigned short* __restrict__ E2)
{
  int gid = blockIdx.x * 256 + threadIdx.x;   // 2560 rows * 128 j4-chunks
  int row = gid >> 7, j4 = (gid & 127) << 2;
  int b = row / 10, o = row - b * 10;
  float4 g = *(const float4*)&G[(size_t)b*HD + j4];
  float e[4] = { g.x * W2[(j4+0)*DOUT + o], g.y * W2[(j4+1)*DOUT + o],
                 g.z * W2[(j4+2)*DOUT + o], g.w * W2[(j4+3)*DOUT + o] };
  unsigned short hi[4], lo[4];
  #pragma unroll
  for (int r = 0; r < 4; r++){
    hi[r] = f2bf(e[r]);
    lo[r] = f2bf(e[r] - bf2f(hi[r]));
  }
  *(ushort4*)&E2[(size_t)row*1024 + j4]       = make_ushort4(hi[0],hi[1],hi[2],hi[3]);
  *(ushort4*)&E2[(size_t)row*1024 + 512 + j4] = make_ushort4(lo[0],lo[1],lo[2],lo[3]);
}

// ---------------- x2 = [xhi | xlo] bf16 ----------------
__global__ __launch_bounds__(256) void k_prepx(
    const float* __restrict__ x, unsigned short* __restrict__ x2)
{
  int gid = blockIdx.x * 256 + threadIdx.x;   // 256 rows * 128 j4-chunks
  int row = gid >> 7, j4 = (gid & 127) << 2;
  float4 v = *(const float4*)&x[(size_t)row*DIN + j4];
  float e[4] = {v.x, v.y, v.z, v.w};
  unsigned short hi[4], lo[4];
  #pragma unroll
  for (int r = 0; r < 4; r++){
    hi[r] = f2bf(e[r]);
    lo[r] = f2bf(e[r] - bf2f(hi[r]));
  }
  *(ushort4*)&x2[(size_t)row*1024 + j4]       = make_ushort4(hi[0],hi[1],hi[2],hi[3]);
  *(ushort4*)&x2[(size_t)row*1024 + 512 + j4] = make_ushort4(lo[0],lo[1],lo[2],lo[3]);
}

// ---------------- M2 = split-bf16 of (Kx .* (E E^T) + delta_{oo'} Kh) ----------------
// grid (40,40): every 64x64 tile computed independently; writes coalesced (no transpose).
__global__ void k_gemm_M(
    const unsigned short* __restrict__ E2, const float* __restrict__ Kx,
    const float* __restrict__ Kh, unsigned short* __restrict__ M2)
{
  const int tid = threadIdx.x;        // 0..63
  const int bi = blockIdx.y, bj = blockIdx.x;
  const int m0 = bi << 6, n0 = bj << 6;
  const int ln = tid & 15, kq = tid >> 4;

  const unsigned short* pa[4];
  const unsigned short* pb[4];
  #pragma unroll
  for (int f = 0; f < 4; f++){
    pa[f] = E2 + (size_t)(m0 + f*16 + ln) * 1024 + kq * 8;
    pb[f] = E2 + (size_t)(n0 + f*16 + ln) * 1024 + kq * 8;
  }

  f32x4 acc[4][4];
  #pragma unroll
  for (int i = 0; i < 4; i++)
    #pragma unroll
    for (int j = 0; j < 4; j++)
      acc[i][j] = (f32x4){0.f, 0.f, 0.f, 0.f};

  s16x8 a0[4], b0[4], a1[4], b1[4];

#define LOAD_AB(Aset, Bset, s) do{                                        \
    const int _ph = (s) >> 4, _kk = ((s) & 15) << 5;                      \
    const int _oa = (_ph == 2 ? 512 : 0) + _kk;                           \
    const int _ob = (_ph == 1 ? 512 : 0) + _kk;                           \
    Aset[0] = *(const s16x8*)(pa[0] + _oa);                               \
    Aset[1] = *(const s16x8*)(pa[1] + _oa);                               \
    Aset[2] = *(const s16x8*)(pa[2] + _oa);                               \
    Aset[3] = *(const s16x8*)(pa[3] + _oa);                               \
    Bset[0] = *(const s16x8*)(pb[0] + _ob);                               \
    Bset[1] = *(const s16x8*)(pb[1] + _ob);                               \
    Bset[2] = *(const s16x8*)(pb[2] + _ob);                               \
    Bset[3] = *(const s16x8*)(pb[3] + _ob);                               \
  }while(0)

#define MFMA_AB(Aset, Bset) do{                                           \
    _Pragma("unroll")                                                     \
    for (int fi = 0; fi < 4; fi++){                                       \
      _Pragma("unroll")                                                   \
      for (int fj = 0; fj < 4; fj++)                                      \
        acc[fi][fj] = __builtin_amdgcn_mfma_f32_16x16x32_bf16(            \
            Aset[fi], Bset[fj], acc[fi][fj], 0, 0, 0);                    \
    }                                                                     \
  }while(0)

  LOAD_AB(a0, b0, 0);
  for (int it = 0; it < 24; ++it){
    const int s1 = 2*it + 1;
    LOAD_AB(a1, b1, s1);
    MFMA_AB(a0, b0);
    const int s2 = 2*it + 2;
    if (s2 < 48) LOAD_AB(a0, b0, s2);
    MFMA_AB(a1, b1);
  }
#undef LOAD_AB
#undef MFMA_AB

  int bmv[4][4], omv[4][4], bnv[4], onv[4];
  #pragma unroll
  for (int f = 0; f < 4; f++){
    int n = n0 + f*16 + ln; bnv[f] = n / 10; onv[f] = n - bnv[f]*10;
    #pragma unroll
    for (int r = 0; r < 4; r++){
      int m = m0 + f*16 + kq*4 + r;
      bmv[f][r] = m / 10; omv[f][r] = m - bmv[f][r]*10;
    }
  }
  #pragma unroll
  for (int fi = 0; fi < 4; fi++)
    #pragma unroll
    for (int r = 0; r < 4; r++){
      const int m = m0 + fi*16 + kq*4 + r;
      #pragma unroll
      for (int fj = 0; fj < 4; fj++){
        const int n = n0 + fj*16 + ln;
        float v = Kx[(size_t)bmv[fi][r]*BB + bnv[fj]] * acc[fi][fj][r];
        if (omv[fi][r] == onv[fj]) v += Kh[(size_t)bmv[fi][r]*BB + bnv[fj]];
        unsigned short hv = f2bf(v);
        M2[(size_t)m*5120 + n]        = hv;
        M2[(size_t)m*5120 + 2560 + n] = f2bf(v - bf2f(hv));
      }
    }
}

// ---------------- T[s] = (x @ eps_W1[s] + eps_b1[s]) * G  via split-bf16 MFMA ----------------
// 512 blocks x 128 thr: tile 128m x 64n. wave w handles m-frags 4w..4w+3.
__global__ __launch_bounds__(128) void k_gemm_T(
    const unsigned short* __restrict__ x2, const float* __restrict__ eW1,
    const float* __restrict__ eb1, const float* __restrict__ G,
    float* __restrict__ T)
{
  const int tid = threadIdx.x;
  const int w = tid >> 6, l = tid & 63;
  const int ln = l & 15, kq = l >> 4;
  const int bid = blockIdx.x;
  const int s = bid >> 4, rem = bid & 15;
  const int m0 = (rem & 1) << 7, n0 = (rem >> 1) << 6;
  const float* Wb = eW1 + (size_t)s * DIN * HD;

  const unsigned short* pa[4];
  #pragma unroll
  for (int f = 0; f < 4; f++)
    pa[f] = x2 + (size_t)(m0 + 16*(4*w + f) + ln) * 1024 + kq * 8;

  f32x4 acc[4][4];
  #pragma unroll
  for (int i = 0; i < 4; i++)
    #pragma unroll
    for (int j = 0; j < 4; j++)
      acc[i][j] = (f32x4){0.f, 0.f, 0.f, 0.f};

  #pragma unroll 2
  for (int k0 = 0; k0 < DIN; k0 += 32){
    float wv[4][8];
    const float* wp = Wb + (size_t)(k0 + kq*8)*HD + n0 + ln;
    #pragma unroll
    for (int i = 0; i < 8; i++)
      #pragma unroll
      for (int f = 0; f < 4; f++)
        wv[f][i] = wp[(size_t)i*HD + 16*f];

    s16x8 ahi[4], alo[4], bhi[4], blo[4];
    #pragma unroll
    for (int f = 0; f < 4; f++){
      ahi[f] = *(const s16x8*)(pa[f] + k0);
      alo[f] = *(const s16x8*)(pa[f] + 512 + k0);
      #pragma unroll
      for (int i = 0; i < 8; i++){
        unsigned short hh = f2bf(wv[f][i]);
        bhi[f][i] = (short)hh;
        blo[f][i] = (short)f2bf(wv[f][i] - bf2f(hh));
      }
    }
    #pragma unroll
    for (int fi = 0; fi < 4; fi++)
      #pragma unroll
      for (int fj = 0; fj < 4; fj++){
        acc[fi][fj] = __builtin_amdgcn_mfma_f32_16x16x32_bf16(ahi[fi], bhi[fj], acc[fi][fj], 0,0,0);
        acc[fi][fj] = __builtin_amdgcn_mfma_f32_16x16x32_bf16(ahi[fi], blo[fj], acc[fi][fj], 0,0,0);
        acc[fi][fj] = __builtin_amdgcn_mfma_f32_16x16x32_bf16(alo[fi], bhi[fj], acc[fi][fj], 0,0,0);
      }
  }

  #pragma unroll
  for (int fj = 0; fj < 4; fj++){
    const int n = n0 + 16*fj + ln;
    const float eb = eb1[(size_t)s*HD + n];
    #pragma unroll
    for (int fi = 0; fi < 4; fi++)
      #pragma unroll
      for (int q = 0; q < 4; q++){
        const int m = m0 + 16*(4*w + fi) + kq*4 + q;
        T[((size_t)s*BB + m)*HD + n] = (acc[fi][fj][q] + eb) * G[(size_t)m*HD + n];
      }
  }
}

// ---------------- bvec (+ out0 for s==0 blocks) ----------------
__global__ __launch_bounds__(256) void k_bvec(
    const float* __restrict__ T, const float* __restrict__ W2,
    const float* __restrict__ h, const float* __restrict__ eW2,
    const float* __restrict__ eb2, const float* __restrict__ b2,
    float* __restrict__ bvec, float* __restrict__ out0, float* __restrict__ rr0_part)
{
  __shared__ __align__(16) float W2t[10][516];
  __shared__ __align__(16) float E2t[10][516];
  __shared__ float wl[4];
  const int tid = threadIdx.x, bid = blockIdx.x;
  const int s = bid / 10;
  const int idx = (bid % 10) * 256 + tid;
  const int b = idx / 10, o = idx - b*10;
  const float* e2 = eW2 + (size_t)s * HD * DOUT;
  for (int i = tid; i < HD*DOUT; i += 256){
    int k = i / 10, oo = i - k*10;
    W2t[oo][k] = W2[i];
    E2t[oo][k] = e2[i];
  }
  __syncthreads();
  const float* Tr = T + ((size_t)s*BB + b) * HD;
  const float* hr = h + (size_t)b * HD;
  const bool do0 = (bid < 10);
  float acc = eb2[s*DOUT + o];
  float a0 = 0.f;
  #pragma unroll 4
  for (int k4 = 0; k4 < HD/4; k4++){
    float4 t4 = *(const float4*)(Tr + (k4<<2));
    float4 h4 = *(const float4*)(hr + (k4<<2));
    float4 w4 = *(const float4*)&W2t[o][k4<<2];
    float4 q4 = *(const float4*)&E2t[o][k4<<2];
    acc += t4.x*w4.x + t4.y*w4.y + t4.z*w4.z + t4.w*w4.w
         + h4.x*q4.x + h4.y*q4.y + h4.z*q4.z + h4.w*q4.w;
    if (do0) a0 += h4.x*w4.x + h4.y*w4.y + h4.z*w4.z + h4.w*w4.w;
  }
  bvec[(size_t)s*NIDX + idx] = acc;
  if (do0) out0[idx] = a0 + b2[o];
  float v = wave_red(acc * acc);
  if ((tid & 63) == 0) wl[tid >> 6] = v;
  __syncthreads();
  if (tid == 0) rr0_part[bid] = wl[0]+wl[1]+wl[2]+wl[3];
}

// ---------------- CG init ----------------
__global__ __launch_bounds__(256) void k_init(
    const float* __restrict__ bvec, const float* __restrict__ rr0_part,
    float* __restrict__ r, float* __restrict__ p, float* __restrict__ a,
    float* __restrict__ basis, float* __restrict__ rr_arr,
    unsigned short* __restrict__ ps2)
{
  int gid = blockIdx.x * 256 + threadIdx.x;
  int s = gid / NIDX, idx = gid - s * NIDX;
  float rr0 = 0.f;
  #pragma unroll
  for (int i = 0; i < 10; i++) rr0 += rr0_part[s*10 + i];
  float bv = bvec[gid];
  r[gid] = bv; p[gid] = bv; a[gid] = 0.f;
  basis[gid] = bv / (sqrtf(rr0) + CG_EPS);
  unsigned short hh = f2bf(bv);
  ps2[(size_t)s*5120 + idx]        = hh;
  ps2[(size_t)s*5120 + 2560 + idx] = f2bf(bv - bf2f(hh));
  if (threadIdx.x == 0) rr_arr[s] = rr0;
}

// ---------------- matvec: Ap_part[kh][s][r] via split-bf16 MFMA ----------------
// grid (80 row-blocks of 32, 2 K-halves), 256 thr (4 waves, wave = 320-col slice).
__global__ __launch_bounds__(256) void k_matvec(
    const unsigned short* __restrict__ M2, const unsigned short* __restrict__ p2,
    float* __restrict__ Ap_part)
{
  __shared__ float red[4][32][33];
  const int tid = threadIdx.x;
  const int w = tid >> 6, l = tid & 63;
  const int ln = l & 15, kq = l >> 4;
  const int R0 = blockIdx.x << 5;
  const int kh = blockIdx.y;
  const int c0 = kh*1280 + w*320;

  const unsigned short* a0p = M2 + (size_t)(R0 + ln)*5120      + c0 + kq*8;
  const unsigned short* a1p = M2 + (size_t)(R0 + 16 + ln)*5120 + c0 + kq*8;
  const unsigned short* q0  = p2 + (size_t)ln*5120             + c0 + kq*8;
  const unsigned short* q1  = p2 + (size_t)(16 + ln)*5120      + c0 + kq*8;

  f32x4 acc[2][2];
  #pragma unroll
  for (int i = 0; i < 2; i++)
    #pragma unroll
    for (int j = 0; j < 2; j++) acc[i][j] = (f32x4){0.f,0.f,0.f,0.f};

  #pragma unroll 2
  for (int ch = 0; ch < 10; ch++){
    const int o = ch * 32;
    s16x8 bh0 = *(const s16x8*)(q0 + o);
    s16x8 bl0 = *(const s16x8*)(q0 + 2560 + o);
    s16x8 bh1 = *(const s16x8*)(q1 + o);
    s16x8 bl1 = *(const s16x8*)(q1 + 2560 + o);
    s16x8 a0h = *(const s16x8*)(a0p + o);
    s16x8 a0l = *(const s16x8*)(a0p + 2560 + o);
    s16x8 a1h = *(const s16x8*)(a1p + o);
    s16x8 a1l = *(const s16x8*)(a1p + 2560 + o);
    acc[0][0] = __builtin_amdgcn_mfma_f32_16x16x32_bf16(a0h, bh0, acc[0][0], 0,0,0);
    acc[0][1] = __builtin_amdgcn_mfma_f32_16x16x32_bf16(a0h, bh1, acc[0][1], 0,0,0);
    acc[1][0] = __builtin_amdgcn_mfma_f32_16x16x32_bf16(a1h, bh0, acc[1][0], 0,0,0);
    acc[1][1] = __builtin_amdgcn_mfma_f32_16x16x32_bf16(a1h, bh1, acc[1][1], 0,0,0);
    acc[0][0] = __builtin_amdgcn_mfma_f32_16x16x32_bf16(a0h, bl0, acc[0][0], 0,0,0);
    acc[0][1] = __builtin_amdgcn_mfma_f32_16x16x32_bf16(a0h, bl1, acc[0][1], 0,0,0);
    acc[1][0] = __builtin_amdgcn_mfma_f32_16x16x32_bf16(a1h, bl0, acc[1][0], 0,0,0);
    acc[1][1] = __builtin_amdgcn_mfma_f32_16x16x32_bf16(a1h, bl1, acc[1][1], 0,0,0);
    acc[0][0] = __builtin_amdgcn_mfma_f32_16x16x32_bf16(a0l, bh0, acc[0][0], 0,0,0);
    acc[0][1] = __builtin_amdgcn_mfma_f32_16x16x32_bf16(a0l, bh1, acc[0][1], 0,0,0);
    acc[1][0] = __builtin_amdgcn_mfma_f32_16x16x32_bf16(a1l, bh0, acc[1][0], 0,0,0);
    acc[1][1] = __builtin_amdgcn_mfma_f32_16x16x32_bf16(a1l, bh1, acc[1][1], 0,0,0);
  }

  #pragma unroll
  for (int f = 0; f < 2; f++)
    #pragma unroll
    for (int g = 0; g < 2; g++)
      #pragma unroll
      for (int q = 0; q < 4; q++)
        red[w][16*f + kq*4 + q][16*g + ln] = acc[f][g][q];
  __syncthreads();
  #pragma unroll
  for (int j = 0; j < 4; j++){
    const int idx = tid + (j << 8);
    const int r = idx & 31, s = idx >> 5;
    float v = red[0][r][s] + red[1][r][s] + red[2][r][s] + red[3][r][s];
    Ap_part[((size_t)kh*NS + s)*NIDX + R0 + r] = v;
  }
}

// ---------------- fused CG update (pAp, alpha, a/r, reortho, beta, p, basis, ps2) ----------------
__global__ __launch_bounds__(256) void k_cg(
    const float* __restrict__ Ap_part, float* __restrict__ rr_arr, int k, int last,
    float* __restrict__ pv, unsigned short* __restrict__ ps2,
    unsigned short* __restrict__ as2,
    float* __restrict__ av, float* __restrict__ rv, float* __restrict__ basis)
{
  __shared__ float wl[4];
  __shared__ float red[4][10];
  __shared__ float cbr[10];
  const int s = blockIdx.x, tid = threadIdx.x;
  const size_t base = (size_t)s * NIDX;
  const float rr = rr_arr[s];

  float ap[10], pvv[10];
  #pragma unroll
  for (int c = 0; c < 10; c++){
    const int idx = tid + (c << 8);
    ap[c]  = Ap_part[base + idx] + Ap_part[(size_t)NS*NIDX + base + idx];
    pvv[c] = pv[base + idx];
  }
  float v = 0.f;
  #pragma unroll
  for (int c = 0; c < 10; c++) v += pvv[c] * ap[c];
  v = wave_red(v);
  if ((tid & 63) == 0) wl[tid >> 6] = v;
  __syncthreads();
  const float pAp = wl[0]+wl[1]+wl[2]+wl[3];
  const float alpha = rr / (pAp + CG_EPS);

  float rn[10];
  #pragma unroll
  for (int c = 0; c < 10; c++){
    const int idx = tid + (c << 8);
    const float an = av[base + idx] + alpha * pvv[c];
    av[base + idx] = an;
    rn[c] = rv[base + idx] - alpha * ap[c];
    if (last){
      unsigned short hh = f2bf(an);
      as2[(size_t)s*5120 + idx]        = hh;
      as2[(size_t)s*5120 + 2560 + idx] = f2bf(an - bf2f(hh));
    }
  }

  for (int j = 0; j <= k; j++){
    float cv = 0.f;
    const float* brow = basis + (size_t)j * (NS*NIDX) + base;
    #pragma unroll
    for (int c = 0; c < 10; c++) cv += brow[tid + (c << 8)] * rn[c];
    cv = wave_red(cv);
    if ((tid & 63) == 0) red[tid >> 6][j] = cv;
  }
  __syncthreads();
  if (tid <= k) cbr[tid] = red[0][tid]+red[1][tid]+red[2][tid]+red[3][tid];
  __syncthreads();

  for (int j = 0; j <= k; j++){
    const float cc = cbr[j];
    const float* brow = basis + (size_t)j * (NS*NIDX) + base;
    #pragma unroll
    for (int c = 0; c < 10; c++) rn[c] -= brow[tid + (c << 8)] * cc;
  }

  float rr2 = 0.f;
  #pragma unroll
  for (int c = 0; c < 10; c++) rr2 += rn[c]*rn[c];
  rr2 = wave_red(rr2);
  __syncthreads();
  if ((tid & 63) == 0) wl[tid >> 6] = rr2;
  __syncthreads();
  const float rrn = wl[0]+wl[1]+wl[2]+wl[3];
  const float beta = rrn / (rr + CG_EPS);
  const float inv  = 1.0f / (sqrtf(rrn) + CG_EPS);

  float* bnew = basis + (size_t)(k+1) * (NS*NIDX) + base;
  #pragma unroll
  for (int c = 0; c < 10; c++){
    const int idx = tid + (c << 8);
    const float pnew = rn[c] + beta * pvv[c];
    rv[base + idx] = rn[c];
    pv[base + idx] = pnew;
    bnew[idx] = rn[c] * inv;
    unsigned short hh = f2bf(pnew);
    ps2[(size_t)s*5120 + idx]        = hh;
    ps2[(size_t)s*5120 + 2560 + idx] = f2bf(pnew - bf2f(hh));
  }
  if (tid == 0) rr_arr[s] = rrn;
}

// ---------------- final: preds = out0 + si*b + (sk-si)*(M a) ----------------
__global__ __launch_bounds__(256) void k_final(
    const float* __restrict__ out0, const float* __restrict__ bvec,
    const float* __restrict__ Ap_part, const float* __restrict__ lp,
    const float* __restrict__ lsi, float* __restrict__ out)
{
  int gid = blockIdx.x * 256 + threadIdx.x;
  int s = gid / NIDX, idx = gid - s * NIDX;
  float sk = expf(-0.5f * lp[0]);
  float si = expf(lsi[0]);
  float ma = Ap_part[gid] + Ap_part[(size_t)NS*NIDX + gid];
  out[gid] = out0[idx] + si * bvec[gid] + (sk - si) * ma;
}

// ---------------- launch ----------------
extern "C" void kernel_launch(void* const* d_in, const int* in_sizes, int n_in,
                              void* d_out, int out_size, void* d_ws, size_t ws_size,
                              hipStream_t stream)
{
  const float* x   = (const float*)d_in[0];
  const float* W1  = (const float*)d_in[1];
  const float* b1  = (const float*)d_in[2];
  const float* W2  = (const float*)d_in[3];
  const float* b2  = (const float*)d_in[4];
  const float* eW1 = (const float*)d_in[5];
  const float* eb1 = (const float*)d_in[6];
  const float* eW2 = (const float*)d_in[7];
  const float* eb2 = (const float*)d_in[8];
  const float* lp  = (const float*)d_in[9];
  const float* lsi = (const float*)d_in[10];
  float* outp = (float*)d_out;

  float* ws = (float*)d_ws;
  float* h        = ws;                       // 131072
  float* G        = h        + 131072;        // 131072
  float* Kx       = G        + 131072;        // 65536
  float* Kh       = Kx       + 65536;         // 65536
  float* E2f      = Kh       + 65536;         // 1310720 (2560x1024 bf16 hi|lo = 2,621,440 ushorts)
  float* x2f      = E2f      + 1310720;       // 131072  (256x1024 bf16 hi|lo)
  float* M2f      = x2f      + 131072;        // 6553600 (2560x5120 bf16 hi|lo); T aliases
  float* out0     = M2f      + 6553600;       // 2560
  float* bvec     = out0     + 2560;          // 81920
  float* rv       = bvec     + 81920;         // 81920
  float* pv       = rv       + 81920;         // 81920
  float* av       = pv       + 81920;         // 81920
  float* basis    = av       + 81920;         // 901120 (11*81920)
  float* Ap_part  = basis    + 901120;        // 163840 (2*32*2560)
  float* ps2f     = Ap_part  + 163840;        // 81920 floats = 32x5120 ushorts x2 halves (FIXED: was 40960)
  float* as2f     = ps2f     + 81920;         // 81920 floats (FIXED: was 40960)
  float* rr0_part = as2f     + 81920;         // 320
  float* rr_arr   = rr0_part + 320;           // 32
  // total 9,948,000 floats = ~39.8 MB

  unsigned short* E2  = (unsigned short*)E2f;
  unsigned short* x2  = (unsigned short*)x2f;
  unsigned short* M2  = (unsigned short*)M2f;
  unsigned short* ps2 = (unsigned short*)ps2f;
  unsigned short* as2 = (unsigned short*)as2f;
  float* T = M2f;   // alias: T (4,194,304 floats) dead before M2 is built

  k_gemm_z   <<<dim3(8,4),   256, 0, stream>>>(x, W1, b1, h, G);
  k_buildE   <<<1280,        256, 0, stream>>>(G, W2, E2);
  k_prepx    <<<128,         256, 0, stream>>>(x, x2);
  k_gemm_kxkh<<<dim3(4,4,2), 256, 0, stream>>>(x, h, Kx, Kh);
  k_gemm_T   <<<512,         128, 0, stream>>>(x2, eW1, eb1, G, T);
  k_bvec     <<<320,         256, 0, stream>>>(T, W2, h, eW2, eb2, b2, bvec, out0, rr0_part);
  k_gemm_M   <<<dim3(40,40), 64,  0, stream>>>(E2, Kx, Kh, M2);  // overwrites T (dead)
  k_init     <<<320,         256, 0, stream>>>(bvec, rr0_part, rv, pv, av, basis, rr_arr, ps2);

  for (int k = 0; k < MAXIT; k++){
    k_matvec<<<dim3(80,2), 256, 0, stream>>>(M2, ps2, Ap_part);
    k_cg    <<<NS,         256, 0, stream>>>(Ap_part, rr_arr, k, (k == MAXIT-1),
                                             pv, ps2, as2, av, rv, basis);
  }

  k_matvec<<<dim3(80,2), 256, 0, stream>>>(M2, as2, Ap_part);
  k_final <<<320,        256, 0, stream>>>(out0, bvec, Ap_part, lp, lsi, outp);
}

// Round 7
// 449.965 us; speedup vs baseline: 2.6904x; 1.0034x over previous
//
#include <hip/hip_runtime.h>
#include <math.h>

#define BB    256      // batch
#define DIN   512
#define HD    512
#define DOUT  10
#define NS    32       // samples
#define NIDX  2560     // BB*DOUT
#define MAXIT 10
#define CG_EPS 1e-12f

typedef __attribute__((ext_vector_type(8))) short s16x8;   // 8 bf16 (4 VGPRs)
typedef __attribute__((ext_vector_type(4))) float f32x4;   // 4 fp32 acc

// ---------------- helpers ----------------
__device__ __forceinline__ float wave_red(float v){
  #pragma unroll
  for (int off = 32; off > 0; off >>= 1) v += __shfl_down(v, off, 64);
  return v;  // lane 0 holds total
}
__device__ __forceinline__ unsigned short f2bf(float f){
  unsigned u = __float_as_uint(f);
  return (unsigned short)((u + 0x7FFFu + ((u >> 16) & 1u)) >> 16);
}
__device__ __forceinline__ float bf2f(unsigned short h){
  return __uint_as_float((unsigned)h << 16);
}

// ---------------- forward: h, G ----------------
__global__ __launch_bounds__(256) void k_gemm_z(
    const float* __restrict__ x, const float* __restrict__ W1,
    const float* __restrict__ b1, float* __restrict__ h, float* __restrict__ G)
{
  __shared__ __align__(16) float Al[16][68];
  __shared__ __align__(16) float Bl[16][64];
  const int tid = threadIdx.x;
  const int m0 = blockIdx.y * 64, n0 = blockIdx.x * 64;
  const int tx = tid & 15, ty = tid >> 4;
  float acc[4][4] = {};
  for (int k0 = 0; k0 < DIN; k0 += 16){
    {
      int m = tid >> 2, kk = (tid & 3) << 2;
      float4 a = *(const float4*)(x + (size_t)(m0+m)*DIN + k0 + kk);
      Al[kk+0][m]=a.x; Al[kk+1][m]=a.y; Al[kk+2][m]=a.z; Al[kk+3][m]=a.w;
    }
    {
      int kk = tid >> 4, n = (tid & 15) << 2;
      *(float4*)&Bl[kk][n] = *(const float4*)(W1 + (size_t)(k0+kk)*HD + n0 + n);
    }
    __syncthreads();
    #pragma unroll
    for (int kk = 0; kk < 16; kk++){
      float4 av = *(const float4*)&Al[kk][ty<<2];
      float4 bv = *(const float4*)&Bl[kk][tx<<2];
      float aa[4]={av.x,av.y,av.z,av.w}, bb[4]={bv.x,bv.y,bv.z,bv.w};
      #pragma unroll
      for (int i=0;i<4;i++)
        #pragma unroll
        for (int j=0;j<4;j++) acc[i][j] += aa[i]*bb[j];
    }
    __syncthreads();
  }
  float4 b4 = *(const float4*)&b1[n0 + (tx<<2)];
  float bbv[4] = {b4.x,b4.y,b4.z,b4.w};
  #pragma unroll
  for (int i=0;i<4;i++){
    int m = m0 + (ty<<2) + i;
    float hh[4], gg[4];
    #pragma unroll
    for (int j=0;j<4;j++){ float t = tanhf(acc[i][j] + bbv[j]); hh[j]=t; gg[j]=1.0f-t*t; }
    *(float4*)&h[(size_t)m*HD + n0 + (tx<<2)] = make_float4(hh[0],hh[1],hh[2],hh[3]);
    *(float4*)&G[(size_t)m*HD + n0 + (tx<<2)] = make_float4(gg[0],gg[1],gg[2],gg[3]);
  }
}

// ---------------- Kx = x x^T + 1 ; Kh = h h^T + 1 ----------------
__global__ __launch_bounds__(256) void k_gemm_kxkh(
    const float* __restrict__ x, const float* __restrict__ h,
    float* __restrict__ Kx, float* __restrict__ Kh)
{
  __shared__ __align__(16) float Al[16][68];
  __shared__ __align__(16) float Bl[16][68];
  const int tid = threadIdx.x;
  const float* A = blockIdx.z ? h : x;
  float* C = blockIdx.z ? Kh : Kx;
  const int m0 = blockIdx.y * 64, n0 = blockIdx.x * 64;
  const int tx = tid & 15, ty = tid >> 4;
  float acc[4][4] = {};
  for (int k0 = 0; k0 < DIN; k0 += 16){
    {
      int m = tid >> 2, kk = (tid & 3) << 2;
      float4 a = *(const float4*)(A + (size_t)(m0+m)*DIN + k0 + kk);
      Al[kk+0][m]=a.x; Al[kk+1][m]=a.y; Al[kk+2][m]=a.z; Al[kk+3][m]=a.w;
      float4 b = *(const float4*)(A + (size_t)(n0+m)*DIN + k0 + kk);
      Bl[kk+0][m]=b.x; Bl[kk+1][m]=b.y; Bl[kk+2][m]=b.z; Bl[kk+3][m]=b.w;
    }
    __syncthreads();
    #pragma unroll
    for (int kk = 0; kk < 16; kk++){
      float4 av = *(const float4*)&Al[kk][ty<<2];
      float4 bv = *(const float4*)&Bl[kk][tx<<2];
      float aa[4]={av.x,av.y,av.z,av.w}, bb[4]={bv.x,bv.y,bv.z,bv.w};
      #pragma unroll
      for (int i=0;i<4;i++)
        #pragma unroll
        for (int j=0;j<4;j++) acc[i][j] += aa[i]*bb[j];
    }
    __syncthreads();
  }
  #pragma unroll
  for (int i=0;i<4;i++){
    int m = m0 + (ty<<2) + i;
    *(float4*)&C[(size_t)m*BB + n0 + (tx<<2)] =
        make_float4(acc[i][0]+1.0f, acc[i][1]+1.0f, acc[i][2]+1.0f, acc[i][3]+1.0f);
  }
}

// ---------------- E2 = [Ehi | Elo] bf16, E[(b,o)][j] = G[b][j]*W2[j][o] ----------------
__global__ __launch_bounds__(256) void k_buildE(
    const float* __restrict__ G, const float* __restrict__ W2,
    unsigned short* __restrict__ E2)
{
  int gid = blockIdx.x * 256 + threadIdx.x;   // 2560 rows * 128 j4-chunks
  int row = gid >> 7, j4 = (gid & 127) << 2;
  int b = row / 10, o = row - b * 10;
  float4 g = *(const float4*)&G[(size_t)b*HD + j4];
  float e[4] = { g.x * W2[(j4+0)*DOUT + o], g.y * W2[(j4+1)*DOUT + o],
                 g.z * W2[(j4+2)*DOUT + o], g.w * W2[(j4+3)*DOUT + o] };
  unsigned short hi[4], lo[4];
  #pragma unroll
  for (int r = 0; r < 4; r++){
    hi[r] = f2bf(e[r]);
    lo[r] = f2bf(e[r] - bf2f(hi[r]));
  }
  *(ushort4*)&E2[(size_t)row*1024 + j4]       = make_ushort4(hi[0],hi[1],hi[2],hi[3]);
  *(ushort4*)&E2[(size_t)row*1024 + 512 + j4] = make_ushort4(lo[0],lo[1],lo[2],lo[3]);
}

// ---------------- x2 = [xhi | xlo] bf16 ----------------
__global__ __launch_bounds__(256) void k_prepx(
    const float* __restrict__ x, unsigned short* __restrict__ x2)
{
  int gid = blockIdx.x * 256 + threadIdx.x;   // 256 rows * 128 j4-chunks
  int row = gid >> 7, j4 = (gid & 127) << 2;
  float4 v = *(const float4*)&x[(size_t)row*DIN + j4];
  float e[4] = {v.x, v.y, v.z, v.w};
  unsigned short hi[4], lo[4];
  #pragma unroll
  for (int r = 0; r < 4; r++){
    hi[r] = f2bf(e[r]);
    lo[r] = f2bf(e[r] - bf2f(hi[r]));
  }
  *(ushort4*)&x2[(size_t)row*1024 + j4]       = make_ushort4(hi[0],hi[1],hi[2],hi[3]);
  *(ushort4*)&x2[(size_t)row*1024 + 512 + j4] = make_ushort4(lo[0],lo[1],lo[2],lo[3]);
}

// ---------------- M2 = split-bf16 of (Kx .* (E E^T) + delta_{oo'} Kh) ----------------
// grid (40,40) x 128 thr (2 waves). In-block split-K: wave w does steps [24w, 24w+24),
// wave 1 dumps acc to LDS, wave 0 reduces + epilogue. Steps: phase = s>>4 (hi*hi, hi*lo,
// lo*hi), k = (s&15)*32.
__global__ __launch_bounds__(128) void k_gemm_M(
    const unsigned short* __restrict__ E2, const float* __restrict__ Kx,
    const float* __restrict__ Kh, unsigned short* __restrict__ M2)
{
  __shared__ float red[64][66];   // 16.9 KB
  const int tid = threadIdx.x;
  const int w = tid >> 6, l = tid & 63;
  const int bi = blockIdx.y, bj = blockIdx.x;
  const int m0 = bi << 6, n0 = bj << 6;
  const int ln = l & 15, kq = l >> 4;

  const unsigned short* pa[4];
  const unsigned short* pb[4];
  #pragma unroll
  for (int f = 0; f < 4; f++){
    pa[f] = E2 + (size_t)(m0 + f*16 + ln) * 1024 + kq * 8;
    pb[f] = E2 + (size_t)(n0 + f*16 + ln) * 1024 + kq * 8;
  }

  f32x4 acc[4][4];
  #pragma unroll
  for (int i = 0; i < 4; i++)
    #pragma unroll
    for (int j = 0; j < 4; j++)
      acc[i][j] = (f32x4){0.f, 0.f, 0.f, 0.f};

  s16x8 a0[4], b0[4], a1[4], b1[4];

#define LOAD_AB(Aset, Bset, s) do{                                        \
    const int _ph = (s) >> 4, _kk = ((s) & 15) << 5;                      \
    const int _oa = (_ph == 2 ? 512 : 0) + _kk;                           \
    const int _ob = (_ph == 1 ? 512 : 0) + _kk;                           \
    Aset[0] = *(const s16x8*)(pa[0] + _oa);                               \
    Aset[1] = *(const s16x8*)(pa[1] + _oa);                               \
    Aset[2] = *(const s16x8*)(pa[2] + _oa);                               \
    Aset[3] = *(const s16x8*)(pa[3] + _oa);                               \
    Bset[0] = *(const s16x8*)(pb[0] + _ob);                               \
    Bset[1] = *(const s16x8*)(pb[1] + _ob);                               \
    Bset[2] = *(const s16x8*)(pb[2] + _ob);                               \
    Bset[3] = *(const s16x8*)(pb[3] + _ob);                               \
  }while(0)

#define MFMA_AB(Aset, Bset) do{                                           \
    _Pragma("unroll")                                                     \
    for (int fi = 0; fi < 4; fi++){                                       \
      _Pragma("unroll")                                                   \
      for (int fj = 0; fj < 4; fj++)                                      \
        acc[fi][fj] = __builtin_amdgcn_mfma_f32_16x16x32_bf16(            \
            Aset[fi], Bset[fj], acc[fi][fj], 0, 0, 0);                    \
    }                                                                     \
  }while(0)

  const int sbase = 24 * w;
  LOAD_AB(a0, b0, sbase);
  for (int it = 0; it < 12; ++it){
    LOAD_AB(a1, b1, sbase + 2*it + 1);
    MFMA_AB(a0, b0);
    if (it < 11) LOAD_AB(a0, b0, sbase + 2*it + 2);
    MFMA_AB(a1, b1);
  }
#undef LOAD_AB
#undef MFMA_AB

  if (w == 1){
    #pragma unroll
    for (int fi = 0; fi < 4; fi++)
      #pragma unroll
      for (int fj = 0; fj < 4; fj++)
        #pragma unroll
        for (int q = 0; q < 4; q++)
          red[16*fi + kq*4 + q][16*fj + ln] = acc[fi][fj][q];
  }
  __syncthreads();
  if (w == 0){
    #pragma unroll
    for (int fi = 0; fi < 4; fi++)
      #pragma unroll
      for (int fj = 0; fj < 4; fj++)
        #pragma unroll
        for (int q = 0; q < 4; q++)
          acc[fi][fj][q] += red[16*fi + kq*4 + q][16*fj + ln];

    int bmv[4][4], omv[4][4], bnv[4], onv[4];
    #pragma unroll
    for (int f = 0; f < 4; f++){
      int n = n0 + f*16 + ln; bnv[f] = n / 10; onv[f] = n - bnv[f]*10;
      #pragma unroll
      for (int r = 0; r < 4; r++){
        int m = m0 + f*16 + kq*4 + r;
        bmv[f][r] = m / 10; omv[f][r] = m - bmv[f][r]*10;
      }
    }
    #pragma unroll
    for (int fi = 0; fi < 4; fi++)
      #pragma unroll
      for (int r = 0; r < 4; r++){
        const int m = m0 + fi*16 + kq*4 + r;
        #pragma unroll
        for (int fj = 0; fj < 4; fj++){
          const int n = n0 + fj*16 + ln;
          float v = Kx[(size_t)bmv[fi][r]*BB + bnv[fj]] * acc[fi][fj][r];
          if (omv[fi][r] == onv[fj]) v += Kh[(size_t)bmv[fi][r]*BB + bnv[fj]];
          unsigned short hv = f2bf(v);
          M2[(size_t)m*5120 + n]        = hv;
          M2[(size_t)m*5120 + 2560 + n] = f2bf(v - bf2f(hv));
        }
      }
  }
}

// ---------------- T[s] = (x @ eps_W1[s] + eps_b1[s]) * G  via split-bf16 MFMA ----------------
// grid (8 n-tiles, 32 samples) x 512 thr (8 waves). Wave w owns m-frags {2w, 2w+1}
// -> block covers full batch (256 rows) x 64 cols; eW1[s] column tile read ONCE.
__global__ __launch_bounds__(512) void k_gemm_T(
    const unsigned short* __restrict__ x2, const float* __restrict__ eW1,
    const float* __restrict__ eb1, const float* __restrict__ G,
    float* __restrict__ T)
{
  const int tid = threadIdx.x;
  const int w = tid >> 6, l = tid & 63;
  const int ln = l & 15, kq = l >> 4;
  const int n0 = blockIdx.x << 6;
  const int s  = blockIdx.y;
  const float* Wb = eW1 + (size_t)s * DIN * HD;

  const unsigned short* pa[2];
  #pragma unroll
  for (int f = 0; f < 2; f++)
    pa[f] = x2 + (size_t)(16*(2*w + f) + ln) * 1024 + kq * 8;

  f32x4 acc[2][4];
  #pragma unroll
  for (int i = 0; i < 2; i++)
    #pragma unroll
    for (int j = 0; j < 4; j++)
      acc[i][j] = (f32x4){0.f, 0.f, 0.f, 0.f};

  #pragma unroll 2
  for (int k0 = 0; k0 < DIN; k0 += 32){
    float wv[4][8];
    const float* wp = Wb + (size_t)(k0 + kq*8)*HD + n0 + ln;
    #pragma unroll
    for (int i = 0; i < 8; i++)
      #pragma unroll
      for (int f = 0; f < 4; f++)
        wv[f][i] = wp[(size_t)i*HD + 16*f];

    s16x8 ahi[2], alo[2], bhi[4], blo[4];
    #pragma unroll
    for (int f = 0; f < 2; f++){
      ahi[f] = *(const s16x8*)(pa[f] + k0);
      alo[f] = *(const s16x8*)(pa[f] + 512 + k0);
    }
    #pragma unroll
    for (int f = 0; f < 4; f++)
      #pragma unroll
      for (int i = 0; i < 8; i++){
        unsigned short hh = f2bf(wv[f][i]);
        bhi[f][i] = (short)hh;
        blo[f][i] = (short)f2bf(wv[f][i] - bf2f(hh));
      }
    #pragma unroll
    for (int fi = 0; fi < 2; fi++)
      #pragma unroll
      for (int fj = 0; fj < 4; fj++){
        acc[fi][fj] = __builtin_amdgcn_mfma_f32_16x16x32_bf16(ahi[fi], bhi[fj], acc[fi][fj], 0,0,0);
        acc[fi][fj] = __builtin_amdgcn_mfma_f32_16x16x32_bf16(ahi[fi], blo[fj], acc[fi][fj], 0,0,0);
        acc[fi][fj] = __builtin_amdgcn_mfma_f32_16x16x32_bf16(alo[fi], bhi[fj], acc[fi][fj], 0,0,0);
      }
  }

  #pragma unroll
  for (int fj = 0; fj < 4; fj++){
    const int n = n0 + 16*fj + ln;
    const float eb = eb1[(size_t)s*HD + n];
    #pragma unroll
    for (int fi = 0; fi < 2; fi++)
      #pragma unroll
      for (int q = 0; q < 4; q++){
        const int m = 16*(2*w + fi) + kq*4 + q;
        T[((size_t)s*BB + m)*HD + n] = (acc[fi][fj][q] + eb) * G[(size_t)m*HD + n];
      }
  }
}

// ---------------- bvec (+ out0 for s==0 blocks) ----------------
__global__ __launch_bounds__(256) void k_bvec(
    const float* __restrict__ T, const float* __restrict__ W2,
    const float* __restrict__ h, const float* __restrict__ eW2,
    const float* __restrict__ eb2, const float* __restrict__ b2,
    float* __restrict__ bvec, float* __restrict__ out0, float* __restrict__ rr0_part)
{
  __shared__ __align__(16) float W2t[10][516];
  __shared__ __align__(16) float E2t[10][516];
  __shared__ float wl[4];
  const int tid = threadIdx.x, bid = blockIdx.x;
  const int s = bid / 10;
  const int idx = (bid % 10) * 256 + tid;
  const int b = idx / 10, o = idx - b*10;
  const float* e2 = eW2 + (size_t)s * HD * DOUT;
  for (int i = tid; i < HD*DOUT; i += 256){
    int k = i / 10, oo = i - k*10;
    W2t[oo][k] = W2[i];
    E2t[oo][k] = e2[i];
  }
  __syncthreads();
  const float* Tr = T + ((size_t)s*BB + b) * HD;
  const float* hr = h + (size_t)b * HD;
  const bool do0 = (bid < 10);
  float acc = eb2[s*DOUT + o];
  float a0 = 0.f;
  #pragma unroll 4
  for (int k4 = 0; k4 < HD/4; k4++){
    float4 t4 = *(const float4*)(Tr + (k4<<2));
    float4 h4 = *(const float4*)(hr + (k4<<2));
    float4 w4 = *(const float4*)&W2t[o][k4<<2];
    float4 q4 = *(const float4*)&E2t[o][k4<<2];
    acc += t4.x*w4.x + t4.y*w4.y + t4.z*w4.z + t4.w*w4.w
         + h4.x*q4.x + h4.y*q4.y + h4.z*q4.z + h4.w*q4.w;
    if (do0) a0 += h4.x*w4.x + h4.y*w4.y + h4.z*w4.z + h4.w*w4.w;
  }
  bvec[(size_t)s*NIDX + idx] = acc;
  if (do0) out0[idx] = a0 + b2[o];
  float v = wave_red(acc * acc);
  if ((tid & 63) == 0) wl[tid >> 6] = v;
  __syncthreads();
  if (tid == 0) rr0_part[bid] = wl[0]+wl[1]+wl[2]+wl[3];
}

// ---------------- CG init ----------------
__global__ __launch_bounds__(256) void k_init(
    const float* __restrict__ bvec, const float* __restrict__ rr0_part,
    float* __restrict__ r, float* __restrict__ p, float* __restrict__ a,
    float* __restrict__ basis, float* __restrict__ rr_arr,
    unsigned short* __restrict__ ps2)
{
  int gid = blockIdx.x * 256 + threadIdx.x;
  int s = gid / NIDX, idx = gid - s * NIDX;
  float rr0 = 0.f;
  #pragma unroll
  for (int i = 0; i < 10; i++) rr0 += rr0_part[s*10 + i];
  float bv = bvec[gid];
  r[gid] = bv; p[gid] = bv; a[gid] = 0.f;
  basis[gid] = bv / (sqrtf(rr0) + CG_EPS);
  unsigned short hh = f2bf(bv);
  ps2[(size_t)s*5120 + idx]        = hh;
  ps2[(size_t)s*5120 + 2560 + idx] = f2bf(bv - bf2f(hh));
  if (threadIdx.x == 0) rr_arr[s] = rr0;
}

// ---------------- matvec: Ap_part[kh][s][r] via split-bf16 MFMA ----------------
// grid (80 row-blocks of 32, 2 K-halves), 256 thr (4 waves, wave = 320-col slice).
__global__ __launch_bounds__(256) void k_matvec(
    const unsigned short* __restrict__ M2, const unsigned short* __restrict__ p2,
    float* __restrict__ Ap_part)
{
  __shared__ float red[4][32][33];
  const int tid = threadIdx.x;
  const int w = tid >> 6, l = tid & 63;
  const int ln = l & 15, kq = l >> 4;
  const int R0 = blockIdx.x << 5;
  const int kh = blockIdx.y;
  const int c0 = kh*1280 + w*320;

  const unsigned short* a0p = M2 + (size_t)(R0 + ln)*5120      + c0 + kq*8;
  const unsigned short* a1p = M2 + (size_t)(R0 + 16 + ln)*5120 + c0 + kq*8;
  const unsigned short* q0  = p2 + (size_t)ln*5120             + c0 + kq*8;
  const unsigned short* q1  = p2 + (size_t)(16 + ln)*5120      + c0 + kq*8;

  f32x4 acc[2][2];
  #pragma unroll
  for (int i = 0; i < 2; i++)
    #pragma unroll
    for (int j = 0; j < 2; j++) acc[i][j] = (f32x4){0.f,0.f,0.f,0.f};

  #pragma unroll 2
  for (int ch = 0; ch < 10; ch++){
    const int o = ch * 32;
    s16x8 bh0 = *(const s16x8*)(q0 + o);
    s16x8 bl0 = *(const s16x8*)(q0 + 2560 + o);
    s16x8 bh1 = *(const s16x8*)(q1 + o);
    s16x8 bl1 = *(const s16x8*)(q1 + 2560 + o);
    s16x8 a0h = *(const s16x8*)(a0p + o);
    s16x8 a0l = *(const s16x8*)(a0p + 2560 + o);
    s16x8 a1h = *(const s16x8*)(a1p + o);
    s16x8 a1l = *(const s16x8*)(a1p + 2560 + o);
    acc[0][0] = __builtin_amdgcn_mfma_f32_16x16x32_bf16(a0h, bh0, acc[0][0], 0,0,0);
    acc[0][1] = __builtin_amdgcn_mfma_f32_16x16x32_bf16(a0h, bh1, acc[0][1], 0,0,0);
    acc[1][0] = __builtin_amdgcn_mfma_f32_16x16x32_bf16(a1h, bh0, acc[1][0], 0,0,0);
    acc[1][1] = __builtin_amdgcn_mfma_f32_16x16x32_bf16(a1h, bh1, acc[1][1], 0,0,0);
    acc[0][0] = __builtin_amdgcn_mfma_f32_16x16x32_bf16(a0h, bl0, acc[0][0], 0,0,0);
    acc[0][1] = __builtin_amdgcn_mfma_f32_16x16x32_bf16(a0h, bl1, acc[0][1], 0,0,0);
    acc[1][0] = __builtin_amdgcn_mfma_f32_16x16x32_bf16(a1h, bl0, acc[1][0], 0,0,0);
    acc[1][1] = __builtin_amdgcn_mfma_f32_16x16x32_bf16(a1h, bl1, acc[1][1], 0,0,0);
    acc[0][0] = __builtin_amdgcn_mfma_f32_16x16x32_bf16(a0l, bh0, acc[0][0], 0,0,0);
    acc[0][1] = __builtin_amdgcn_mfma_f32_16x16x32_bf16(a0l, bh1, acc[0][1], 0,0,0);
    acc[1][0] = __builtin_amdgcn_mfma_f32_16x16x32_bf16(a1l, bh0, acc[1][0], 0,0,0);
    acc[1][1] = __builtin_amdgcn_mfma_f32_16x16x32_bf16(a1l, bh1, acc[1][1], 0,0,0);
  }

  #pragma unroll
  for (int f = 0; f < 2; f++)
    #pragma unroll
    for (int g = 0; g < 2; g++)
      #pragma unroll
      for (int q = 0; q < 4; q++)
        red[w][16*f + kq*4 + q][16*g + ln] = acc[f][g][q];
  __syncthreads();
  #pragma unroll
  for (int j = 0; j < 4; j++){
    const int idx = tid + (j << 8);
    const int r = idx & 31, s = idx >> 5;
    float v = red[0][r][s] + red[1][r][s] + red[2][r][s] + red[3][r][s];
    Ap_part[((size_t)kh*NS + s)*NIDX + R0 + r] = v;
  }
}

// ---------------- fused CG update (pAp, alpha, a/r, reortho, beta, p, basis, ps2) ----------------
__global__ __launch_bounds__(256) void k_cg(
    const float* __restrict__ Ap_part, float* __restrict__ rr_arr, int k, int last,
    float* __restrict__ pv, unsigned short* __restrict__ ps2,
    unsigned short* __restrict__ as2,
    float* __restrict__ av, float* __restrict__ rv, float* __restrict__ basis)
{
  __shared__ float wl[4];
  __shared__ float red[4][10];
  __shared__ float cbr[10];
  const int s = blockIdx.x, tid = threadIdx.x;
  const size_t base = (size_t)s * NIDX;
  const float rr = rr_arr[s];

  float ap[10], pvv[10];
  #pragma unroll
  for (int c = 0; c < 10; c++){
    const int idx = tid + (c << 8);
    ap[c]  = Ap_part[base + idx] + Ap_part[(size_t)NS*NIDX + base + idx];
    pvv[c] = pv[base + idx];
  }
  float v = 0.f;
  #pragma unroll
  for (int c = 0; c < 10; c++) v += pvv[c] * ap[c];
  v = wave_red(v);
  if ((tid & 63) == 0) wl[tid >> 6] = v;
  __syncthreads();
  const float pAp = wl[0]+wl[1]+wl[2]+wl[3];
  const float alpha = rr / (pAp + CG_EPS);

  float rn[10];
  #pragma unroll
  for (int c = 0; c < 10; c++){
    const int idx = tid + (c << 8);
    const float an = av[base + idx] + alpha * pvv[c];
    av[base + idx] = an;
    rn[c] = rv[base + idx] - alpha * ap[c];
    if (last){
      unsigned short hh = f2bf(an);
      as2[(size_t)s*5120 + idx]        = hh;
      as2[(size_t)s*5120 + 2560 + idx] = f2bf(an - bf2f(hh));
    }
  }

  for (int j = 0; j <= k; j++){
    float cv = 0.f;
    const float* brow = basis + (size_t)j * (NS*NIDX) + base;
    #pragma unroll
    for (int c = 0; c < 10; c++) cv += brow[tid + (c << 8)] * rn[c];
    cv = wave_red(cv);
    if ((tid & 63) == 0) red[tid >> 6][j] = cv;
  }
  __syncthreads();
  if (tid <= k) cbr[tid] = red[0][tid]+red[1][tid]+red[2][tid]+red[3][tid];
  __syncthreads();

  for (int j = 0; j <= k; j++){
    const float cc = cbr[j];
    const float* brow = basis + (size_t)j * (NS*NIDX) + base;
    #pragma unroll
    for (int c = 0; c < 10; c++) rn[c] -= brow[tid + (c << 8)] * cc;
  }

  float rr2 = 0.f;
  #pragma unroll
  for (int c = 0; c < 10; c++) rr2 += rn[c]*rn[c];
  rr2 = wave_red(rr2);
  __syncthreads();
  if ((tid & 63) == 0) wl[tid >> 6] = rr2;
  __syncthreads();
  const float rrn = wl[0]+wl[1]+wl[2]+wl[3];
  const float beta = rrn / (rr + CG_EPS);
  const float inv  = 1.0f / (sqrtf(rrn) + CG_EPS);

  float* bnew = basis + (size_t)(k+1) * (NS*NIDX) + base;
  #pragma unroll
  for (int c = 0; c < 10; c++){
    const int idx = tid + (c << 8);
    const float pnew = rn[c] + beta * pvv[c];
    rv[base + idx] = rn[c];
    pv[base + idx] = pnew;
    bnew[idx] = rn[c] * inv;
    unsigned short hh = f2bf(pnew);
    ps2[(size_t)s*5120 + idx]        = hh;
    ps2[(size_t)s*5120 + 2560 + idx] = f2bf(pnew - bf2f(hh));
  }
  if (tid == 0) rr_arr[s] = rrn;
}

// ---------------- final: preds = out0 + si*b + (sk-si)*(M a) ----------------
__global__ __launch_bounds__(256) void k_final(
    const float* __restrict__ out0, const float* __restrict__ bvec,
    const float* __restrict__ Ap_part, const float* __restrict__ lp,
    const float* __restrict__ lsi, float* __restrict__ out)
{
  int gid = blockIdx.x * 256 + threadIdx.x;
  int s = gid / NIDX, idx = gid - s * NIDX;
  float sk = expf(-0.5f * lp[0]);
  float si = expf(lsi[0]);
  float ma = Ap_part[gid] + Ap_part[(size_t)NS*NIDX + gid];
  out[gid] = out0[idx] + si * bvec[gid] + (sk - si) * ma;
}

// ---------------- launch ----------------
extern "C" void kernel_launch(void* const* d_in, const int* in_sizes, int n_in,
                              void* d_out, int out_size, void* d_ws, size_t ws_size,
                              hipStream_t stream)
{
  const float* x   = (const float*)d_in[0];
  const float* W1  = (const float*)d_in[1];
  const float* b1  = (const float*)d_in[2];
  const float* W2  = (const float*)d_in[3];
  const float* b2  = (const float*)d_in[4];
  const float* eW1 = (const float*)d_in[5];
  const float* eb1 = (const float*)d_in[6];
  const float* eW2 = (const float*)d_in[7];
  const float* eb2 = (const float*)d_in[8];
  const float* lp  = (const float*)d_in[9];
  const float* lsi = (const float*)d_in[10];
  float* outp = (float*)d_out;

  float* ws = (float*)d_ws;
  float* h        = ws;                       // 131072
  float* G        = h        + 131072;        // 131072
  float* Kx       = G        + 131072;        // 65536
  float* Kh       = Kx       + 65536;         // 65536
  float* E2f      = Kh       + 65536;         // 1310720 (2560x1024 bf16 hi|lo)
  float* x2f      = E2f      + 1310720;       // 131072  (256x1024 bf16 hi|lo)
  float* M2f      = x2f      + 131072;        // 6553600 (2560x5120 bf16 hi|lo); T aliases
  float* out0     = M2f      + 6553600;       // 2560
  float* bvec     = out0     + 2560;          // 81920
  float* rv       = bvec     + 81920;         // 81920
  float* pv       = rv       + 81920;         // 81920
  float* av       = pv       + 81920;         // 81920
  float* basis    = av       + 81920;         // 901120 (11*81920)
  float* Ap_part  = basis    + 901120;        // 163840 (2*32*2560)
  float* ps2f     = Ap_part  + 163840;        // 81920 floats (32x5120 ushorts hi|lo)
  float* as2f     = ps2f     + 81920;         // 81920 floats
  float* rr0_part = as2f     + 81920;         // 320
  float* rr_arr   = rr0_part + 320;           // 32
  // total ~9.95M floats = ~39.8 MB

  unsigned short* E2  = (unsigned short*)E2f;
  unsigned short* x2  = (unsigned short*)x2f;
  unsigned short* M2  = (unsigned short*)M2f;
  unsigned short* ps2 = (unsigned short*)ps2f;
  unsigned short* as2 = (unsigned short*)as2f;
  float* T = M2f;   // alias: T (4,194,304 floats) dead before M2 is built

  k_gemm_z   <<<dim3(8,4),   256, 0, stream>>>(x, W1, b1, h, G);
  k_buildE   <<<1280,        256, 0, stream>>>(G, W2, E2);
  k_prepx    <<<128,         256, 0, stream>>>(x, x2);
  k_gemm_kxkh<<<dim3(4,4,2), 256, 0, stream>>>(x, h, Kx, Kh);
  k_gemm_T   <<<dim3(8,32),  512, 0, stream>>>(x2, eW1, eb1, G, T);
  k_bvec     <<<320,         256, 0, stream>>>(T, W2, h, eW2, eb2, b2, bvec, out0, rr0_part);
  k_gemm_M   <<<dim3(40,40), 128, 0, stream>>>(E2, Kx, Kh, M2);  // overwrites T (dead)
  k_init     <<<320,         256, 0, stream>>>(bvec, rr0_part, rv, pv, av, basis, rr_arr, ps2);

  for (int k = 0; k < MAXIT; k++){
    k_matvec<<<dim3(80,2), 256, 0, stream>>>(M2, ps2, Ap_part);
    k_cg    <<<NS,         256, 0, stream>>>(Ap_part, rr_arr, k, (k == MAXIT-1),
                                             pv, ps2, as2, av, rv, basis);
  }

  k_matvec<<<dim3(80,2), 256, 0, stream>>>(M2, as2, Ap_part);
  k_final <<<320,        256, 0, stream>>>(out0, bvec, Ap_part, lp, lsi, outp);
}

// Round 8
// 397.073 us; speedup vs baseline: 3.0488x; 1.1332x over previous
//
#include <hip/hip_runtime.h>
#include <math.h>

#define BB    256      // batch
#define DIN   512
#define HD    512
#define DOUT  10
#define NS    32       // samples
#define NIDX  2560     // BB*DOUT
#define MAXIT 10
#define CG_EPS 1e-12f

typedef __attribute__((ext_vector_type(8))) short s16x8;   // 8 bf16 (4 VGPRs)
typedef __attribute__((ext_vector_type(4))) float f32x4;   // 4 fp32 acc

// ---------------- helpers ----------------
__device__ __forceinline__ float wave_red(float v){
  #pragma unroll
  for (int off = 32; off > 0; off >>= 1) v += __shfl_down(v, off, 64);
  return v;  // lane 0 holds total
}
__device__ __forceinline__ unsigned short f2bf(float f){
  unsigned u = __float_as_uint(f);
  return (unsigned short)((u + 0x7FFFu + ((u >> 16) & 1u)) >> 16);
}
__device__ __forceinline__ float bf2f(unsigned short h){
  return __uint_as_float((unsigned)h << 16);
}

typedef const __attribute__((address_space(1))) unsigned short gus_t;
typedef __attribute__((address_space(3))) unsigned short lus_t;
__device__ __forceinline__ void gload16(const unsigned short* g, unsigned short* l){
  // async global->LDS, 16B/lane; LDS dest = wave-uniform base + lane*16
  __builtin_amdgcn_global_load_lds((gus_t*)g, (lus_t*)l, 16, 0, 0);
}

// ---------------- forward: h, G ----------------
__global__ __launch_bounds__(256) void k_gemm_z(
    const float* __restrict__ x, const float* __restrict__ W1,
    const float* __restrict__ b1, float* __restrict__ h, float* __restrict__ G)
{
  __shared__ __align__(16) float Al[16][68];
  __shared__ __align__(16) float Bl[16][64];
  const int tid = threadIdx.x;
  const int m0 = blockIdx.y * 64, n0 = blockIdx.x * 64;
  const int tx = tid & 15, ty = tid >> 4;
  float acc[4][4] = {};
  for (int k0 = 0; k0 < DIN; k0 += 16){
    {
      int m = tid >> 2, kk = (tid & 3) << 2;
      float4 a = *(const float4*)(x + (size_t)(m0+m)*DIN + k0 + kk);
      Al[kk+0][m]=a.x; Al[kk+1][m]=a.y; Al[kk+2][m]=a.z; Al[kk+3][m]=a.w;
    }
    {
      int kk = tid >> 4, n = (tid & 15) << 2;
      *(float4*)&Bl[kk][n] = *(const float4*)(W1 + (size_t)(k0+kk)*HD + n0 + n);
    }
    __syncthreads();
    #pragma unroll
    for (int kk = 0; kk < 16; kk++){
      float4 av = *(const float4*)&Al[kk][ty<<2];
      float4 bv = *(const float4*)&Bl[kk][tx<<2];
      float aa[4]={av.x,av.y,av.z,av.w}, bb[4]={bv.x,bv.y,bv.z,bv.w};
      #pragma unroll
      for (int i=0;i<4;i++)
        #pragma unroll
        for (int j=0;j<4;j++) acc[i][j] += aa[i]*bb[j];
    }
    __syncthreads();
  }
  float4 b4 = *(const float4*)&b1[n0 + (tx<<2)];
  float bbv[4] = {b4.x,b4.y,b4.z,b4.w};
  #pragma unroll
  for (int i=0;i<4;i++){
    int m = m0 + (ty<<2) + i;
    float hh[4], gg[4];
    #pragma unroll
    for (int j=0;j<4;j++){ float t = tanhf(acc[i][j] + bbv[j]); hh[j]=t; gg[j]=1.0f-t*t; }
    *(float4*)&h[(size_t)m*HD + n0 + (tx<<2)] = make_float4(hh[0],hh[1],hh[2],hh[3]);
    *(float4*)&G[(size_t)m*HD + n0 + (tx<<2)] = make_float4(gg[0],gg[1],gg[2],gg[3]);
  }
}

// ---------------- Kx = x x^T + 1 ; Kh = h h^T + 1 ----------------
__global__ __launch_bounds__(256) void k_gemm_kxkh(
    const float* __restrict__ x, const float* __restrict__ h,
    float* __restrict__ Kx, float* __restrict__ Kh)
{
  __shared__ __align__(16) float Al[16][68];
  __shared__ __align__(16) float Bl[16][68];
  const int tid = threadIdx.x;
  const float* A = blockIdx.z ? h : x;
  float* C = blockIdx.z ? Kh : Kx;
  const int m0 = blockIdx.y * 64, n0 = blockIdx.x * 64;
  const int tx = tid & 15, ty = tid >> 4;
  float acc[4][4] = {};
  for (int k0 = 0; k0 < DIN; k0 += 16){
    {
      int m = tid >> 2, kk = (tid & 3) << 2;
      float4 a = *(const float4*)(A + (size_t)(m0+m)*DIN + k0 + kk);
      Al[kk+0][m]=a.x; Al[kk+1][m]=a.y; Al[kk+2][m]=a.z; Al[kk+3][m]=a.w;
      float4 b = *(const float4*)(A + (size_t)(n0+m)*DIN + k0 + kk);
      Bl[kk+0][m]=b.x; Bl[kk+1][m]=b.y; Bl[kk+2][m]=b.z; Bl[kk+3][m]=b.w;
    }
    __syncthreads();
    #pragma unroll
    for (int kk = 0; kk < 16; kk++){
      float4 av = *(const float4*)&Al[kk][ty<<2];
      float4 bv = *(const float4*)&Bl[kk][tx<<2];
      float aa[4]={av.x,av.y,av.z,av.w}, bb[4]={bv.x,bv.y,bv.z,bv.w};
      #pragma unroll
      for (int i=0;i<4;i++)
        #pragma unroll
        for (int j=0;j<4;j++) acc[i][j] += aa[i]*bb[j];
    }
    __syncthreads();
  }
  #pragma unroll
  for (int i=0;i<4;i++){
    int m = m0 + (ty<<2) + i;
    *(float4*)&C[(size_t)m*BB + n0 + (tx<<2)] =
        make_float4(acc[i][0]+1.0f, acc[i][1]+1.0f, acc[i][2]+1.0f, acc[i][3]+1.0f);
  }
}

// ---------------- E2 = [Ehi | Elo] bf16, E[(b,o)][j] = G[b][j]*W2[j][o] ----------------
__global__ __launch_bounds__(256) void k_buildE(
    const float* __restrict__ G, const float* __restrict__ W2,
    unsigned short* __restrict__ E2)
{
  int gid = blockIdx.x * 256 + threadIdx.x;   // 2560 rows * 128 j4-chunks
  int row = gid >> 7, j4 = (gid & 127) << 2;
  int b = row / 10, o = row - b * 10;
  float4 g = *(const float4*)&G[(size_t)b*HD + j4];
  float e[4] = { g.x * W2[(j4+0)*DOUT + o], g.y * W2[(j4+1)*DOUT + o],
                 g.z * W2[(j4+2)*DOUT + o], g.w * W2[(j4+3)*DOUT + o] };
  unsigned short hi[4], lo[4];
  #pragma unroll
  for (int r = 0; r < 4; r++){
    hi[r] = f2bf(e[r]);
    lo[r] = f2bf(e[r] - bf2f(hi[r]));
  }
  *(ushort4*)&E2[(size_t)row*1024 + j4]       = make_ushort4(hi[0],hi[1],hi[2],hi[3]);
  *(ushort4*)&E2[(size_t)row*1024 + 512 + j4] = make_ushort4(lo[0],lo[1],lo[2],lo[3]);
}

// ---------------- x2 = [xhi | xlo] bf16 ----------------
__global__ __launch_bounds__(256) void k_prepx(
    const float* __restrict__ x, unsigned short* __restrict__ x2)
{
  int gid = blockIdx.x * 256 + threadIdx.x;   // 256 rows * 128 j4-chunks
  int row = gid >> 7, j4 = (gid & 127) << 2;
  float4 v = *(const float4*)&x[(size_t)row*DIN + j4];
  float e[4] = {v.x, v.y, v.z, v.w};
  unsigned short hi[4], lo[4];
  #pragma unroll
  for (int r = 0; r < 4; r++){
    hi[r] = f2bf(e[r]);
    lo[r] = f2bf(e[r] - bf2f(hi[r]));
  }
  *(ushort4*)&x2[(size_t)row*1024 + j4]       = make_ushort4(hi[0],hi[1],hi[2],hi[3]);
  *(ushort4*)&x2[(size_t)row*1024 + 512 + j4] = make_ushort4(lo[0],lo[1],lo[2],lo[3]);
}

// ---------------- M2 = split-bf16 of (Kx .* (E E^T) + delta_{oo'} Kh) ----------------
// LDS-staged MFMA GEMM (m97 structure). Tile 128m x 64n, grid (40 n, 20 m), 128 thr
// (2 waves; wave w = 64 m-rows x 64 n). K-loop: 24 steps of BK=64 over 3 phases
// (hi*hi, hi*lo, lo*hi) via phase-dependent GLOBAL column offsets. Staging via
// global_load_lds w=16 with XOR-swizzled source chunks (T2; rule #21: linear LDS dest
// + inverse-swizzled src + swizzled ds_read).
__global__ __launch_bounds__(128) void k_gemm_M(
    const unsigned short* __restrict__ E2, const float* __restrict__ Kx,
    const float* __restrict__ Kh, unsigned short* __restrict__ M2)
{
  __shared__ __align__(16) unsigned short As[128*64];   // 16 KB, row stride 64 elems
  __shared__ __align__(16) unsigned short Bs[64*64];    // 8 KB
  const int tid = threadIdx.x;
  const int w = tid >> 6, l = tid & 63;
  const int ln = l & 15, kq = l >> 4;
  const int m0 = blockIdx.y << 7, n0 = blockIdx.x << 6;

  // staging: chunk idx = c*128 + tid -> row = c*16 + (tid>>3), colchunk = tid&7,
  // source colchunk = (tid&7) ^ (row&7)   [swizzle involution]
  const int srow = tid >> 3;
  const int scc  = (tid & 7) ^ (srow & 7);
  const unsigned short* gA = E2 + (size_t)(m0 + srow)*1024 + scc*8;
  const unsigned short* gB = E2 + (size_t)(n0 + srow)*1024 + scc*8;
  unsigned short* lA = As + ((tid & 64) << 3);   // wave-uniform base (+1024/call)
  unsigned short* lB = Bs + ((tid & 64) << 3);

  f32x4 acc[4][4];
  #pragma unroll
  for (int i = 0; i < 4; i++)
    #pragma unroll
    for (int j = 0; j < 4; j++)
      acc[i][j] = (f32x4){0.f, 0.f, 0.f, 0.f};

  const int xs = ln & 7;   // read-side swizzle key (row&7 == ln&7 for 16-aligned frag rows)

  for (int t = 0; t < 24; ++t){
    const int p = t >> 3, k8 = t & 7;
    const int oa = ((p == 2) ? 512 : 0) + (k8 << 6);
    const int ob = ((p == 1) ? 512 : 0) + (k8 << 6);
    #pragma unroll
    for (int c = 0; c < 8; c++)
      gload16(gA + (size_t)c*16*1024 + oa, lA + c*1024);
    #pragma unroll
    for (int c = 0; c < 4; c++)
      gload16(gB + (size_t)c*16*1024 + ob, lB + c*1024);
    __syncthreads();   // drains vmcnt (gload_lds) before LDS reads

    #pragma unroll
    for (int kk = 0; kk < 2; kk++){
      const int kc = kq + (kk << 2);          // 8-elem chunk index 0..7
      const int co = (kc ^ xs) << 3;          // swizzled elem offset within row
      s16x8 af[4], bf[4];
      #pragma unroll
      for (int f = 0; f < 4; f++){
        af[f] = *(const s16x8*)(As + ((w<<6) + (f<<4) + ln)*64 + co);
        bf[f] = *(const s16x8*)(Bs + ((f<<4) + ln)*64 + co);
      }
      #pragma unroll
      for (int fi = 0; fi < 4; fi++)
        #pragma unroll
        for (int fj = 0; fj < 4; fj++)
          acc[fi][fj] = __builtin_amdgcn_mfma_f32_16x16x32_bf16(
              af[fi], bf[fj], acc[fi][fj], 0, 0, 0);
    }
    __syncthreads();   // LDS reuse next step
  }

  // epilogue: v = Kx*acc (+ Kh on o-diagonal); split-bf16 write, coalesced rows
  const int mb = m0 + (w << 6);
  int bmv[4][4], omv[4][4], bnv[4], onv[4];
  #pragma unroll
  for (int f = 0; f < 4; f++){
    int n = n0 + f*16 + ln; bnv[f] = n / 10; onv[f] = n - bnv[f]*10;
    #pragma unroll
    for (int r = 0; r < 4; r++){
      int m = mb + f*16 + kq*4 + r;
      bmv[f][r] = m / 10; omv[f][r] = m - bmv[f][r]*10;
    }
  }
  #pragma unroll
  for (int fi = 0; fi < 4; fi++)
    #pragma unroll
    for (int r = 0; r < 4; r++){
      const int m = mb + fi*16 + kq*4 + r;
      #pragma unroll
      for (int fj = 0; fj < 4; fj++){
        const int n = n0 + fj*16 + ln;
        float v = Kx[(size_t)bmv[fi][r]*BB + bnv[fj]] * acc[fi][fj][r];
        if (omv[fi][r] == onv[fj]) v += Kh[(size_t)bmv[fi][r]*BB + bnv[fj]];
        unsigned short hv = f2bf(v);
        M2[(size_t)m*5120 + n]        = hv;
        M2[(size_t)m*5120 + 2560 + n] = f2bf(v - bf2f(hv));
      }
    }
}

// ---------------- T[s] = (x @ eps_W1[s] + eps_b1[s]) * G  via split-bf16 MFMA ----------------
// grid (8 n-tiles, 32 samples) x 512 thr (8 waves). Wave w owns m-frags {2w, 2w+1}.
__global__ __launch_bounds__(512) void k_gemm_T(
    const unsigned short* __restrict__ x2, const float* __restrict__ eW1,
    const float* __restrict__ eb1, const float* __restrict__ G,
    float* __restrict__ T)
{
  const int tid = threadIdx.x;
  const int w = tid >> 6, l = tid & 63;
  const int ln = l & 15, kq = l >> 4;
  const int n0 = blockIdx.x << 6;
  const int s  = blockIdx.y;
  const float* Wb = eW1 + (size_t)s * DIN * HD;

  const unsigned short* pa[2];
  #pragma unroll
  for (int f = 0; f < 2; f++)
    pa[f] = x2 + (size_t)(16*(2*w + f) + ln) * 1024 + kq * 8;

  f32x4 acc[2][4];
  #pragma unroll
  for (int i = 0; i < 2; i++)
    #pragma unroll
    for (int j = 0; j < 4; j++)
      acc[i][j] = (f32x4){0.f, 0.f, 0.f, 0.f};

  #pragma unroll 2
  for (int k0 = 0; k0 < DIN; k0 += 32){
    float wv[4][8];
    const float* wp = Wb + (size_t)(k0 + kq*8)*HD + n0 + ln;
    #pragma unroll
    for (int i = 0; i < 8; i++)
      #pragma unroll
      for (int f = 0; f < 4; f++)
        wv[f][i] = wp[(size_t)i*HD + 16*f];

    s16x8 ahi[2], alo[2], bhi[4], blo[4];
    #pragma unroll
    for (int f = 0; f < 2; f++){
      ahi[f] = *(const s16x8*)(pa[f] + k0);
      alo[f] = *(const s16x8*)(pa[f] + 512 + k0);
    }
    #pragma unroll
    for (int f = 0; f < 4; f++)
      #pragma unroll
      for (int i = 0; i < 8; i++){
        unsigned short hh = f2bf(wv[f][i]);
        bhi[f][i] = (short)hh;
        blo[f][i] = (short)f2bf(wv[f][i] - bf2f(hh));
      }
    #pragma unroll
    for (int fi = 0; fi < 2; fi++)
      #pragma unroll
      for (int fj = 0; fj < 4; fj++){
        acc[fi][fj] = __builtin_amdgcn_mfma_f32_16x16x32_bf16(ahi[fi], bhi[fj], acc[fi][fj], 0,0,0);
        acc[fi][fj] = __builtin_amdgcn_mfma_f32_16x16x32_bf16(ahi[fi], blo[fj], acc[fi][fj], 0,0,0);
        acc[fi][fj] = __builtin_amdgcn_mfma_f32_16x16x32_bf16(alo[fi], bhi[fj], acc[fi][fj], 0,0,0);
      }
  }

  #pragma unroll
  for (int fj = 0; fj < 4; fj++){
    const int n = n0 + 16*fj + ln;
    const float eb = eb1[(size_t)s*HD + n];
    #pragma unroll
    for (int fi = 0; fi < 2; fi++)
      #pragma unroll
      for (int q = 0; q < 4; q++){
        const int m = 16*(2*w + fi) + kq*4 + q;
        T[((size_t)s*BB + m)*HD + n] = (acc[fi][fj][q] + eb) * G[(size_t)m*HD + n];
      }
  }
}

// ---------------- bvec (+ out0 for s==0 blocks) ----------------
__global__ __launch_bounds__(256) void k_bvec(
    const float* __restrict__ T, const float* __restrict__ W2,
    const float* __restrict__ h, const float* __restrict__ eW2,
    const float* __restrict__ eb2, const float* __restrict__ b2,
    float* __restrict__ bvec, float* __restrict__ out0, float* __restrict__ rr0_part)
{
  __shared__ __align__(16) float W2t[10][516];
  __shared__ __align__(16) float E2t[10][516];
  __shared__ float wl[4];
  const int tid = threadIdx.x, bid = blockIdx.x;
  const int s = bid / 10;
  const int idx = (bid % 10) * 256 + tid;
  const int b = idx / 10, o = idx - b*10;
  const float* e2 = eW2 + (size_t)s * HD * DOUT;
  for (int i = tid; i < HD*DOUT; i += 256){
    int k = i / 10, oo = i - k*10;
    W2t[oo][k] = W2[i];
    E2t[oo][k] = e2[i];
  }
  __syncthreads();
  const float* Tr = T + ((size_t)s*BB + b) * HD;
  const float* hr = h + (size_t)b * HD;
  const bool do0 = (bid < 10);
  float acc = eb2[s*DOUT + o];
  float a0 = 0.f;
  #pragma unroll 4
  for (int k4 = 0; k4 < HD/4; k4++){
    float4 t4 = *(const float4*)(Tr + (k4<<2));
    float4 h4 = *(const float4*)(hr + (k4<<2));
    float4 w4 = *(const float4*)&W2t[o][k4<<2];
    float4 q4 = *(const float4*)&E2t[o][k4<<2];
    acc += t4.x*w4.x + t4.y*w4.y + t4.z*w4.z + t4.w*w4.w
         + h4.x*q4.x + h4.y*q4.y + h4.z*q4.z + h4.w*q4.w;
    if (do0) a0 += h4.x*w4.x + h4.y*w4.y + h4.z*w4.z + h4.w*w4.w;
  }
  bvec[(size_t)s*NIDX + idx] = acc;
  if (do0) out0[idx] = a0 + b2[o];
  float v = wave_red(acc * acc);
  if ((tid & 63) == 0) wl[tid >> 6] = v;
  __syncthreads();
  if (tid == 0) rr0_part[bid] = wl[0]+wl[1]+wl[2]+wl[3];
}

// ---------------- CG init ----------------
__global__ __launch_bounds__(256) void k_init(
    const float* __restrict__ bvec, const float* __restrict__ rr0_part,
    float* __restrict__ r, float* __restrict__ p, float* __restrict__ a,
    float* __restrict__ basis, float* __restrict__ rr_arr,
    unsigned short* __restrict__ ps2)
{
  int gid = blockIdx.x * 256 + threadIdx.x;
  int s = gid / NIDX, idx = gid - s * NIDX;
  float rr0 = 0.f;
  #pragma unroll
  for (int i = 0; i < 10; i++) rr0 += rr0_part[s*10 + i];
  float bv = bvec[gid];
  r[gid] = bv; p[gid] = bv; a[gid] = 0.f;
  basis[gid] = bv / (sqrtf(rr0) + CG_EPS);
  unsigned short hh = f2bf(bv);
  ps2[(size_t)s*5120 + idx]        = hh;
  ps2[(size_t)s*5120 + 2560 + idx] = f2bf(bv - bf2f(hh));
  if (threadIdx.x == 0) rr_arr[s] = rr0;
}

// ---------------- matvec: Ap_part[kh][s][r] via split-bf16 MFMA ----------------
// grid (80 row-blocks of 32, 4 K-quarters), 256 thr (4 waves, wave = 160-col slice).
__global__ __launch_bounds__(256) void k_matvec(
    const unsigned short* __restrict__ M2, const unsigned short* __restrict__ p2,
    float* __restrict__ Ap_part)
{
  __shared__ float red[4][32][33];
  const int tid = threadIdx.x;
  const int w = tid >> 6, l = tid & 63;
  const int ln = l & 15, kq = l >> 4;
  const int R0 = blockIdx.x << 5;
  const int kh = blockIdx.y;                 // 0..3
  const int c0 = kh*640 + w*160;

  const unsigned short* a0p = M2 + (size_t)(R0 + ln)*5120      + c0 + kq*8;
  const unsigned short* a1p = M2 + (size_t)(R0 + 16 + ln)*5120 + c0 + kq*8;
  const unsigned short* q0  = p2 + (size_t)ln*5120             + c0 + kq*8;
  const unsigned short* q1  = p2 + (size_t)(16 + ln)*5120      + c0 + kq*8;

  f32x4 acc[2][2];
  #pragma unroll
  for (int i = 0; i < 2; i++)
    #pragma unroll
    for (int j = 0; j < 2; j++) acc[i][j] = (f32x4){0.f,0.f,0.f,0.f};

  #pragma unroll
  for (int ch = 0; ch < 5; ch++){
    const int o = ch * 32;
    s16x8 bh0 = *(const s16x8*)(q0 + o);
    s16x8 bl0 = *(const s16x8*)(q0 + 2560 + o);
    s16x8 bh1 = *(const s16x8*)(q1 + o);
    s16x8 bl1 = *(const s16x8*)(q1 + 2560 + o);
    s16x8 a0h = *(const s16x8*)(a0p + o);
    s16x8 a0l = *(const s16x8*)(a0p + 2560 + o);
    s16x8 a1h = *(const s16x8*)(a1p + o);
    s16x8 a1l = *(const s16x8*)(a1p + 2560 + o);
    acc[0][0] = __builtin_amdgcn_mfma_f32_16x16x32_bf16(a0h, bh0, acc[0][0], 0,0,0);
    acc[0][1] = __builtin_amdgcn_mfma_f32_16x16x32_bf16(a0h, bh1, acc[0][1], 0,0,0);
    acc[1][0] = __builtin_amdgcn_mfma_f32_16x16x32_bf16(a1h, bh0, acc[1][0], 0,0,0);
    acc[1][1] = __builtin_amdgcn_mfma_f32_16x16x32_bf16(a1h, bh1, acc[1][1], 0,0,0);
    acc[0][0] = __builtin_amdgcn_mfma_f32_16x16x32_bf16(a0h, bl0, acc[0][0], 0,0,0);
    acc[0][1] = __builtin_amdgcn_mfma_f32_16x16x32_bf16(a0h, bl1, acc[0][1], 0,0,0);
    acc[1][0] = __builtin_amdgcn_mfma_f32_16x16x32_bf16(a1h, bl0, acc[1][0], 0,0,0);
    acc[1][1] = __builtin_amdgcn_mfma_f32_16x16x32_bf16(a1h, bl1, acc[1][1], 0,0,0);
    acc[0][0] = __builtin_amdgcn_mfma_f32_16x16x32_bf16(a0l, bh0, acc[0][0], 0,0,0);
    acc[0][1] = __builtin_amdgcn_mfma_f32_16x16x32_bf16(a0l, bh1, acc[0][1], 0,0,0);
    acc[1][0] = __builtin_amdgcn_mfma_f32_16x16x32_bf16(a1l, bh0, acc[1][0], 0,0,0);
    acc[1][1] = __builtin_amdgcn_mfma_f32_16x16x32_bf16(a1l, bh1, acc[1][1], 0,0,0);
  }

  #pragma unroll
  for (int f = 0; f < 2; f++)
    #pragma unroll
    for (int g = 0; g < 2; g++)
      #pragma unroll
      for (int q = 0; q < 4; q++)
        red[w][16*f + kq*4 + q][16*g + ln] = acc[f][g][q];
  __syncthreads();
  #pragma unroll
  for (int j = 0; j < 4; j++){
    const int idx = tid + (j << 8);
    const int r = idx & 31, s = idx >> 5;
    float v = red[0][r][s] + red[1][r][s] + red[2][r][s] + red[3][r][s];
    Ap_part[((size_t)kh*NS + s)*NIDX + R0 + r] = v;
  }
}

// ---------------- fused CG update (pAp, alpha, a/r, reortho, beta, p, basis, ps2) ----------------
__global__ __launch_bounds__(256) void k_cg(
    const float* __restrict__ Ap_part, float* __restrict__ rr_arr, int k, int last,
    float* __restrict__ pv, unsigned short* __restrict__ ps2,
    unsigned short* __restrict__ as2,
    float* __restrict__ av, float* __restrict__ rv, float* __restrict__ basis)
{
  __shared__ float wl[4];
  __shared__ float red[4][10];
  __shared__ float cbr[10];
  const int s = blockIdx.x, tid = threadIdx.x;
  const size_t base = (size_t)s * NIDX;
  const float rr = rr_arr[s];

  float ap[10], pvv[10];
  #pragma unroll
  for (int c = 0; c < 10; c++){
    const int idx = tid + (c << 8);
    float apv = 0.f;
    #pragma unroll
    for (int kc = 0; kc < 4; kc++)
      apv += Ap_part[((size_t)kc*NS + s)*NIDX + idx];
    ap[c]  = apv;
    pvv[c] = pv[base + idx];
  }
  float v = 0.f;
  #pragma unroll
  for (int c = 0; c < 10; c++) v += pvv[c] * ap[c];
  v = wave_red(v);
  if ((tid & 63) == 0) wl[tid >> 6] = v;
  __syncthreads();
  const float pAp = wl[0]+wl[1]+wl[2]+wl[3];
  const float alpha = rr / (pAp + CG_EPS);

  float rn[10];
  #pragma unroll
  for (int c = 0; c < 10; c++){
    const int idx = tid + (c << 8);
    const float an = av[base + idx] + alpha * pvv[c];
    av[base + idx] = an;
    rn[c] = rv[base + idx] - alpha * ap[c];
    if (last){
      unsigned short hh = f2bf(an);
      as2[(size_t)s*5120 + idx]        = hh;
      as2[(size_t)s*5120 + 2560 + idx] = f2bf(an - bf2f(hh));
    }
  }

  for (int j = 0; j <= k; j++){
    float cv = 0.f;
    const float* brow = basis + (size_t)j * (NS*NIDX) + base;
    #pragma unroll
    for (int c = 0; c < 10; c++) cv += brow[tid + (c << 8)] * rn[c];
    cv = wave_red(cv);
    if ((tid & 63) == 0) red[tid >> 6][j] = cv;
  }
  __syncthreads();
  if (tid <= k) cbr[tid] = red[0][tid]+red[1][tid]+red[2][tid]+red[3][tid];
  __syncthreads();

  for (int j = 0; j <= k; j++){
    const float cc = cbr[j];
    const float* brow = basis + (size_t)j * (NS*NIDX) + base;
    #pragma unroll
    for (int c = 0; c < 10; c++) rn[c] -= brow[tid + (c << 8)] * cc;
  }

  float rr2 = 0.f;
  #pragma unroll
  for (int c = 0; c < 10; c++) rr2 += rn[c]*rn[c];
  rr2 = wave_red(rr2);
  __syncthreads();
  if ((tid & 63) == 0) wl[tid >> 6] = rr2;
  __syncthreads();
  const float rrn = wl[0]+wl[1]+wl[2]+wl[3];
  const float beta = rrn / (rr + CG_EPS);
  const float inv  = 1.0f / (sqrtf(rrn) + CG_EPS);

  float* bnew = basis + (size_t)(k+1) * (NS*NIDX) + base;
  #pragma unroll
  for (int c = 0; c < 10; c++){
    const int idx = tid + (c << 8);
    const float pnew = rn[c] + beta * pvv[c];
    rv[base + idx] = rn[c];
    pv[base + idx] = pnew;
    bnew[idx] = rn[c] * inv;
    unsigned short hh = f2bf(pnew);
    ps2[(size_t)s*5120 + idx]        = hh;
    ps2[(size_t)s*5120 + 2560 + idx] = f2bf(pnew - bf2f(hh));
  }
  if (tid == 0) rr_arr[s] = rrn;
}

// ---------------- final: preds = out0 + si*b + (sk-si)*(M a) ----------------
__global__ __launch_bounds__(256) void k_final(
    const float* __restrict__ out0, const float* __restrict__ bvec,
    const float* __restrict__ Ap_part, const float* __restrict__ lp,
    const float* __restrict__ lsi, float* __restrict__ out)
{
  int gid = blockIdx.x * 256 + threadIdx.x;
  int s = gid / NIDX, idx = gid - s * NIDX;
  float sk = expf(-0.5f * lp[0]);
  float si = expf(lsi[0]);
  float ma = 0.f;
  #pragma unroll
  for (int kc = 0; kc < 4; kc++) ma += Ap_part[(size_t)kc*NS*NIDX + gid];
  out[gid] = out0[idx] + si * bvec[gid] + (sk - si) * ma;
}

// ---------------- launch ----------------
extern "C" void kernel_launch(void* const* d_in, const int* in_sizes, int n_in,
                              void* d_out, int out_size, void* d_ws, size_t ws_size,
                              hipStream_t stream)
{
  const float* x   = (const float*)d_in[0];
  const float* W1  = (const float*)d_in[1];
  const float* b1  = (const float*)d_in[2];
  const float* W2  = (const float*)d_in[3];
  const float* b2  = (const float*)d_in[4];
  const float* eW1 = (const float*)d_in[5];
  const float* eb1 = (const float*)d_in[6];
  const float* eW2 = (const float*)d_in[7];
  const float* eb2 = (const float*)d_in[8];
  const float* lp  = (const float*)d_in[9];
  const float* lsi = (const float*)d_in[10];
  float* outp = (float*)d_out;

  float* ws = (float*)d_ws;
  float* h        = ws;                       // 131072
  float* G        = h        + 131072;        // 131072
  float* Kx       = G        + 131072;        // 65536
  float* Kh       = Kx       + 65536;         // 65536
  float* E2f      = Kh       + 65536;         // 1310720 (2560x1024 bf16 hi|lo)
  float* x2f      = E2f      + 1310720;       // 131072  (256x1024 bf16 hi|lo)
  float* M2f      = x2f      + 131072;        // 6553600 (2560x5120 bf16 hi|lo); T aliases
  float* out0     = M2f      + 6553600;       // 2560
  float* bvec     = out0     + 2560;          // 81920
  float* rv       = bvec     + 81920;         // 81920
  float* pv       = rv       + 81920;         // 81920
  float* av       = pv       + 81920;         // 81920
  float* basis    = av       + 81920;         // 901120 (11*81920)
  float* Ap_part  = basis    + 901120;        // 327680 (4*32*2560)
  float* ps2f     = Ap_part  + 327680;        // 81920 floats (32x5120 ushorts hi|lo)
  float* as2f     = ps2f     + 81920;         // 81920 floats
  float* rr0_part = as2f     + 81920;         // 320
  float* rr_arr   = rr0_part + 320;           // 32
  // total ~10.11M floats = ~40.4 MB

  unsigned short* E2  = (unsigned short*)E2f;
  unsigned short* x2  = (unsigned short*)x2f;
  unsigned short* M2  = (unsigned short*)M2f;
  unsigned short* ps2 = (unsigned short*)ps2f;
  unsigned short* as2 = (unsigned short*)as2f;
  float* T = M2f;   // alias: T (4,194,304 floats) dead before M2 is built

  k_gemm_z   <<<dim3(8,4),   256, 0, stream>>>(x, W1, b1, h, G);
  k_buildE   <<<1280,        256, 0, stream>>>(G, W2, E2);
  k_prepx    <<<128,         256, 0, stream>>>(x, x2);
  k_gemm_kxkh<<<dim3(4,4,2), 256, 0, stream>>>(x, h, Kx, Kh);
  k_gemm_T   <<<dim3(8,32),  512, 0, stream>>>(x2, eW1, eb1, G, T);
  k_bvec     <<<320,         256, 0, stream>>>(T, W2, h, eW2, eb2, b2, bvec, out0, rr0_part);
  k_gemm_M   <<<dim3(40,20), 128, 0, stream>>>(E2, Kx, Kh, M2);  // overwrites T (dead)
  k_init     <<<320,         256, 0, stream>>>(bvec, rr0_part, rv, pv, av, basis, rr_arr, ps2);

  for (int k = 0; k < MAXIT; k++){
    k_matvec<<<dim3(80,4), 256, 0, stream>>>(M2, ps2, Ap_part);
    k_cg    <<<NS,         256, 0, stream>>>(Ap_part, rr_arr, k, (k == MAXIT-1),
                                             pv, ps2, as2, av, rv, basis);
  }

  k_matvec<<<dim3(80,4), 256, 0, stream>>>(M2, as2, Ap_part);
  k_final <<<320,        256, 0, stream>>>(out0, bvec, Ap_part, lp, lsi, outp);
}